// Round 11
// baseline (253.876 us; speedup 1.0000x reference)
//
#include <hip/hip_runtime.h>
#include <hip/hip_bf16.h>

#define D_MODEL 1024
#define N_HEADS 16
#define HEAD_DIM 64
#define BATCH 4
#define SEQ 2048
#define M_ROWS (BATCH * SEQ)  // 8192

typedef __attribute__((ext_vector_type(8))) __bf16 bf16x8;
typedef __attribute__((ext_vector_type(8))) short short8;
typedef __attribute__((ext_vector_type(4))) float f32x4;

static __device__ __forceinline__ unsigned short f2bf_rne(float f) {
  unsigned int u = __float_as_uint(f);
  u += 0x7FFFu + ((u >> 16) & 1u);
  return (unsigned short)(u >> 16);
}

// pack two f32 -> two bf16 (RNE) in one instruction; no builtin on gfx950 (T12 recipe)
static __device__ __forceinline__ unsigned int cvtpk_bf16(float a, float b) {
  unsigned int r;
  asm("v_cvt_pk_bf16_f32 %0, %1, %2" : "=v"(r) : "v"(a), "v"(b));
  return r;
}

#if __has_builtin(__builtin_amdgcn_exp2f)
#define EXP2F(x) __builtin_amdgcn_exp2f(x)
#else
#define EXP2F(x) exp2f(x)
#endif

static __device__ __forceinline__ void gl_lds16(const unsigned short* g, unsigned short* l) {
  __builtin_amdgcn_global_load_lds((const __attribute__((address_space(1))) unsigned int*)g,
                                   (__attribute__((address_space(3))) unsigned int*)l, 16, 0, 0);
}

// raw barrier (no vmcnt(0) drain!) + compiler memory fence
#define BAR() asm volatile("s_barrier" ::: "memory")
#define WAIT_LGKM0() asm volatile("s_waitcnt lgkmcnt(0)" ::: "memory")
#define WAIT_VM(N) asm volatile("s_waitcnt vmcnt(" #N ")" ::: "memory")

// ---------------- merged fp32 -> bf16 conversion (x + 4 weights), one launch ----------------
__global__ __launch_bounds__(256) void cvt_all(const float* __restrict__ x,
                                               const float* __restrict__ wq,
                                               const float* __restrict__ wk,
                                               const float* __restrict__ wv,
                                               const float* __restrict__ wo,
                                               unsigned short* __restrict__ xb,
                                               unsigned short* __restrict__ wqb,
                                               unsigned short* __restrict__ wkb,
                                               unsigned short* __restrict__ wvb,
                                               unsigned short* __restrict__ wob) {
  const int bid = blockIdx.x;
  const float* src;
  unsigned short* dst;
  int i;
  if (bid < 8192) {
    src = x; dst = xb; i = bid * 256 + threadIdx.x;
  } else {
    int r = bid - 8192;
    int w = r >> 10;
    i = (r & 1023) * 256 + threadIdx.x;
    switch (w) {
      case 0: src = wq; dst = wqb; break;
      case 1: src = wk; dst = wkb; break;
      case 2: src = wv; dst = wvb; break;
      default: src = wo; dst = wob; break;
    }
  }
  float4 f = reinterpret_cast<const float4*>(src)[i];
  ushort4 o;
  o.x = f2bf_rne(f.x); o.y = f2bf_rne(f.y); o.z = f2bf_rne(f.z); o.w = f2bf_rne(f.w);
  reinterpret_cast<ushort4*>(dst)[i] = o;
}

// ---------------- Q+K GEMM: 256x256 tile, 8-phase counted-vmcnt schedule (m201) ------------
// Grid = 2 weights x 32 x 4 = 256 blocks = EXACTLY 1 round at 1 block/CU (128 KiB LDS).
__global__ __launch_bounds__(512, 2) void qk_gemm8(const unsigned short* __restrict__ A,
                                                   const unsigned short* __restrict__ Wq,
                                                   const unsigned short* __restrict__ Wk,
                                                   unsigned short* __restrict__ Qo,
                                                   unsigned short* __restrict__ Ko) {
  // layout (ushort units): A: [buf][half] 4 x 8192 at 0; B: 4 x 8192 at 32768. 128 KiB total.
  __shared__ __align__(16) unsigned short smem[65536];

  const int bid = blockIdx.x;
  const int wgid = (bid & 7) * 32 + (bid >> 3);  // XCD-chunked, bijective (256 = 8*32)
  const int widx = wgid >> 7;                    // 0=Q 1=K
  const int rem = wgid & 127;
  const int bm = rem >> 2, bn = rem & 3;

  const unsigned short* Bw = (widx == 0) ? Wq : Wk;

  const int t = threadIdx.x;
  const int wave = t >> 6, lane = t & 63;
  const int wmi = wave >> 2, wni = wave & 3;  // 2 x 4 wave grid
  const int lr = lane & 15, quad = lane >> 4;

  // staging slots: slot s in [0,1024) -> LDS linear s*16B; row r=s>>3, src chunk=(s&7)^(r&7)
  const int r0 = t >> 3, c0 = (t & 7) ^ (r0 & 7);
  const int s1 = t + 512;
  const int r1 = s1 >> 3, c1 = (s1 & 7) ^ (r1 & 7);
  const unsigned short* Asrc0 = A + (size_t)(bm * 256 + r0) * D_MODEL + c0 * 8;
  const unsigned short* Asrc1 = A + (size_t)(bm * 256 + r1) * D_MODEL + c1 * 8;
  const unsigned short* Bsrc0 = Bw + (size_t)(bn * 256 + r0) * D_MODEL + c0 * 8;
  const unsigned short* Bsrc1 = Bw + (size_t)(bn * 256 + r1) * D_MODEL + c1 * 8;

  auto stageA = [&](int kt, int buf, int half) {
    unsigned short* dst = &smem[(buf * 2 + half) * 8192];
    const size_t go = (size_t)half * (128 * D_MODEL) + kt * 64;
    gl_lds16(Asrc0 + go, dst + t * 8);
    gl_lds16(Asrc1 + go, dst + s1 * 8);
  };
  auto stageB = [&](int kt, int buf, int half) {
    unsigned short* dst = &smem[32768 + (buf * 2 + half) * 8192];
    const size_t go = (size_t)half * (128 * D_MODEL) + kt * 64;
    gl_lds16(Bsrc0 + go, dst + t * 8);
    gl_lds16(Bsrc1 + go, dst + s1 * 8);
  };

  f32x4 acc[8][4] = {};
  bf16x8 bfrag[4][2];

  // prologue: A(0),B(0) -> buf0 ; B(1) -> buf1 ; A(1) staged at iter0 p0/p1
  stageA(0, 0, 0); stageA(0, 0, 1);
  stageB(0, 0, 0); stageB(0, 0, 1);
  stageB(1, 1, 0); stageB(1, 1, 1);
  WAIT_VM(4);  // drain A(0)+B(0) (8 oldest); B(1) stays in flight
  BAR();

  const int brow0 = (wni & 1) * 64;
  for (int j = 0; j < 8; ++j) {
#pragma unroll
    for (int tb = 0; tb < 2; ++tb) {
      const unsigned short* As = &smem[(tb * 2 + wmi) * 8192];
      const unsigned short* Bs = &smem[32768 + (tb * 2 + (wni >> 1)) * 8192];
#pragma unroll
      for (int qd = 0; qd < 4; ++qd) {
        const int p = tb * 4 + qd;
        if (qd == 0) {  // whole-K-tile B fragments, kept in regs for 4 phases
#pragma unroll
          for (int n = 0; n < 4; ++n)
#pragma unroll
            for (int ks = 0; ks < 2; ++ks) {
              const int row = brow0 + n * 16 + lr;
              bfrag[n][ks] = __builtin_bit_cast(
                  bf16x8, *reinterpret_cast<const short8*>(
                              &Bs[row * 64 + (((ks * 4 + quad) ^ (row & 7)) * 8)]));
            }
        }
        bf16x8 af[2][2];
#pragma unroll
        for (int mi = 0; mi < 2; ++mi)
#pragma unroll
          for (int ks = 0; ks < 2; ++ks) {
            const int row = (qd * 2 + mi) * 16 + lr;
            af[mi][ks] = __builtin_bit_cast(
                bf16x8, *reinterpret_cast<const short8*>(
                            &As[row * 64 + (((ks * 4 + quad) ^ (row & 7)) * 8)]));
          }
        // stage schedule: each target buffer freed (all waves' reads done + barrier) before issue
        if (p == 0) stageA(2 * j + 1, 1, 0);
        if (p == 1) { stageA(2 * j + 1, 1, 1); if (j < 7) stageB(2 * j + 2, 0, 0); }
        if (p == 2) { if (j < 7) stageB(2 * j + 2, 0, 1); }
        if (p == 4) { if (j < 7) stageA(2 * j + 2, 0, 0); }
        if (p == 5) { if (j < 7) { stageA(2 * j + 2, 0, 1); stageB(2 * j + 3, 1, 0); } }
        if (p == 6) { if (j < 7) stageB(2 * j + 3, 1, 1); }
        BAR();
        WAIT_LGKM0();
        __builtin_amdgcn_s_setprio(1);
#pragma unroll
        for (int mi = 0; mi < 2; ++mi)
#pragma unroll
          for (int n = 0; n < 4; ++n)
#pragma unroll
            for (int ks = 0; ks < 2; ++ks)
              acc[qd * 2 + mi][n] = __builtin_amdgcn_mfma_f32_16x16x32_bf16(
                  af[mi][ks], bfrag[n][ks], acc[qd * 2 + mi][n], 0, 0, 0);
        __builtin_amdgcn_s_setprio(0);
        // counted waits, FIFO drain: p3 ensures tile 2j+1 (buf1) landed, p7 ensures 2j+2 (buf0)
        if (p == 3) { if (j < 7) { WAIT_VM(4); } else { WAIT_VM(0); } }
        if (p == 7) { if (j < 7) { WAIT_VM(4); } }
        BAR();
      }
    }
  }

  unsigned short* Cp = (widx == 0) ? Qo : Ko;
  const float sc = (widx == 0) ? 0.18033688f : 1.0f;  // Q: 1/8 * log2(e)
#pragma unroll
  for (int m = 0; m < 8; ++m) {
#pragma unroll
    for (int n = 0; n < 4; ++n) {
      const int col = bn * 256 + wni * 64 + n * 16 + lr;
#pragma unroll
      for (int r = 0; r < 4; ++r) {
        const int row = bm * 256 + wmi * 128 + m * 16 + quad * 4 + r;
        Cp[(size_t)row * D_MODEL + col] = f2bf_rne(acc[m][n][r] * sc);
      }
    }
  }
}

// ---------------- V GEMM: 128x128 tile, dbuf + XOR swizzle + transpose epilogue -----------
__global__ __launch_bounds__(256) void v_gemm(const unsigned short* __restrict__ A,
                                              const unsigned short* __restrict__ Bw,
                                              unsigned short* __restrict__ Vt) {
  __shared__ __align__(16) unsigned short smem[16384];
  const int t = threadIdx.x;
  const int bn = blockIdx.x, bm = blockIdx.y;
  const int K = D_MODEL;
  const int wave = t >> 6, lane = t & 63;
  const int wm = (wave >> 1) * 64, wn = (wave & 1) * 64;
  const int lr = lane & 15, quad = lane >> 4;
  const int rxor = (lr >> 1) & 3;

  const int g0 = wave * 128 + lane, g1 = g0 + 64;
  const int r0 = g0 >> 2, c0 = (((g0 & 3) ^ ((r0 >> 1) & 3)) << 3);
  const int r1 = g1 >> 2, c1 = (((g1 & 3) ^ ((r1 >> 1) & 3)) << 3);
  const unsigned short* Arow0 = A + (size_t)(bm * 128 + r0) * K + c0;
  const unsigned short* Arow1 = A + (size_t)(bm * 128 + r1) * K + c1;
  const unsigned short* Brow0 = Bw + (size_t)(bn * 128 + r0) * K + c0;
  const unsigned short* Brow1 = Bw + (size_t)(bn * 128 + r1) * K + c1;

  f32x4 acc[4][4] = {};

  gl_lds16(Arow0, &smem[g0 * 8]);
  gl_lds16(Arow1, &smem[g1 * 8]);
  gl_lds16(Brow0, &smem[4096 + g0 * 8]);
  gl_lds16(Brow1, &smem[4096 + g1 * 8]);
  __syncthreads();

  for (int it = 0; it < 32; it++) {
    const int cur = (it & 1) * 8192;
    if (it + 1 < 32) {
      const int nxt = 8192 - cur;
      const int k1 = (it + 1) * 32;
      gl_lds16(Arow0 + k1, &smem[nxt + g0 * 8]);
      gl_lds16(Arow1 + k1, &smem[nxt + g1 * 8]);
      gl_lds16(Brow0 + k1, &smem[nxt + 4096 + g0 * 8]);
      gl_lds16(Brow1 + k1, &smem[nxt + 4096 + g1 * 8]);
    }
    const unsigned short* As = &smem[cur];
    const unsigned short* Bs = &smem[cur + 4096];

    bf16x8 af[4], bfr[4];
#pragma unroll
    for (int mt = 0; mt < 4; mt++)
      af[mt] = __builtin_bit_cast(
          bf16x8,
          *reinterpret_cast<const short8*>(&As[(wm + mt * 16 + lr) * 32 + (quad ^ rxor) * 8]));
#pragma unroll
    for (int nt = 0; nt < 4; nt++)
      bfr[nt] = __builtin_bit_cast(
          bf16x8,
          *reinterpret_cast<const short8*>(&Bs[(wn + nt * 16 + lr) * 32 + (quad ^ rxor) * 8]));
#pragma unroll
    for (int mt = 0; mt < 4; mt++)
#pragma unroll
      for (int nt = 0; nt < 4; nt++)
        acc[mt][nt] = __builtin_amdgcn_mfma_f32_16x16x32_bf16(af[mt], bfr[nt], acc[mt][nt], 0, 0, 0);
    __syncthreads();
  }

  // V transpose through LDS (reuses smem), write Vt[(b*16+h2)*64+d][s]
  const int b = bm >> 4;
  const int s0 = (bm & 15) * 128;
#pragma unroll
  for (int half = 0; half < 2; half++) {
    __syncthreads();
    if ((wave & 1) == half) {
#pragma unroll
      for (int nt = 0; nt < 4; nt++) {
#pragma unroll
        for (int mt = 0; mt < 4; mt++) {
#pragma unroll
          for (int r = 0; r < 4; r++) {
            int cl = nt * 16 + lr;                 // d within this 64-col half
            int rl = wm + mt * 16 + quad * 4 + r;  // s within 128-row tile
            smem[cl * 136 + rl] = f2bf_rne(acc[mt][nt][r]);
          }
        }
      }
    }
    __syncthreads();
    const int h2 = bn * 2 + half;
    const size_t rowbase = ((size_t)(b * N_HEADS + h2)) * HEAD_DIM;
#pragma unroll
    for (int i = 0; i < 4; i++) {
      int c = i * 256 + t;
      int d = c >> 4, s8 = (c & 15) * 8;
      uint4 v = *reinterpret_cast<const uint4*>(&smem[d * 136 + s8]);
      *reinterpret_cast<uint4*>(Vt + (rowbase + d) * SEQ + s0 + s8) = v;
    }
  }
}

// ---------------- O-projection GEMM: 128x128 tile, dbuf + XOR swizzle (r13 proven) --------
__global__ __launch_bounds__(256) void gemm_bt_f32(const unsigned short* __restrict__ A,
                                                   const unsigned short* __restrict__ Bw,
                                                   float* __restrict__ Cp,
                                                   int M, int N, int K) {
  __shared__ __align__(16) unsigned short smem[16384];
  const int t = threadIdx.x;
  const int bn = blockIdx.x, bm = blockIdx.y;
  const int wave = t >> 6, lane = t & 63;
  const int wm = (wave >> 1) * 64, wn = (wave & 1) * 64;
  const int lr = lane & 15, quad = lane >> 4;
  const int rxor = (lr >> 1) & 3;

  const int g0 = wave * 128 + lane, g1 = g0 + 64;
  const int r0 = g0 >> 2, c0 = (((g0 & 3) ^ ((r0 >> 1) & 3)) << 3);
  const int r1 = g1 >> 2, c1 = (((g1 & 3) ^ ((r1 >> 1) & 3)) << 3);
  const unsigned short* Arow0 = A + (size_t)(bm * 128 + r0) * K + c0;
  const unsigned short* Arow1 = A + (size_t)(bm * 128 + r1) * K + c1;
  const unsigned short* Brow0 = Bw + (size_t)(bn * 128 + r0) * K + c0;
  const unsigned short* Brow1 = Bw + (size_t)(bn * 128 + r1) * K + c1;

  f32x4 acc[4][4] = {};

  gl_lds16(Arow0, &smem[g0 * 8]);
  gl_lds16(Arow1, &smem[g1 * 8]);
  gl_lds16(Brow0, &smem[4096 + g0 * 8]);
  gl_lds16(Brow1, &smem[4096 + g1 * 8]);
  __syncthreads();

  for (int it = 0; it < 32; it++) {
    const int cur = (it & 1) * 8192;
    if (it + 1 < 32) {
      const int nxt = 8192 - cur;
      const int k1 = (it + 1) * 32;
      gl_lds16(Arow0 + k1, &smem[nxt + g0 * 8]);
      gl_lds16(Arow1 + k1, &smem[nxt + g1 * 8]);
      gl_lds16(Brow0 + k1, &smem[nxt + 4096 + g0 * 8]);
      gl_lds16(Brow1 + k1, &smem[nxt + 4096 + g1 * 8]);
    }
    const unsigned short* As = &smem[cur];
    const unsigned short* Bs = &smem[cur + 4096];

    bf16x8 af[4], bfr[4];
#pragma unroll
    for (int mt = 0; mt < 4; mt++)
      af[mt] = __builtin_bit_cast(
          bf16x8,
          *reinterpret_cast<const short8*>(&As[(wm + mt * 16 + lr) * 32 + (quad ^ rxor) * 8]));
#pragma unroll
    for (int nt = 0; nt < 4; nt++)
      bfr[nt] = __builtin_bit_cast(
          bf16x8,
          *reinterpret_cast<const short8*>(&Bs[(wn + nt * 16 + lr) * 32 + (quad ^ rxor) * 8]));
#pragma unroll
    for (int mt = 0; mt < 4; mt++)
#pragma unroll
      for (int nt = 0; nt < 4; nt++)
        acc[mt][nt] = __builtin_amdgcn_mfma_f32_16x16x32_bf16(af[mt], bfr[nt], acc[mt][nt], 0, 0, 0);
    __syncthreads();
  }

#pragma unroll
  for (int mt = 0; mt < 4; mt++) {
#pragma unroll
    for (int nt = 0; nt < 4; nt++) {
      int col = bn * 128 + wn + nt * 16 + lr;
#pragma unroll
      for (int r = 0; r < 4; r++) {
        int row = bm * 128 + wm + mt * 16 + quad * 4 + r;
        Cp[(size_t)row * N + col] = acc[mt][nt][r];
      }
    }
  }
}

// ---------------- causal flash attention v12: 32 q-rows per wave (2 row-tiles A/B) --------
// attn is LDS-BW-bound (r6 counters): all 8 waves re-read identical K/V fragments. Each wave
// now owns TWO 16-row tiles (A: rows [0,128), B: rows [128,256) of a 256-row phase) so every
// kf/vv LDS read feeds 2 MFMAs -> K/V LDS bytes per q-row halve. Fully-masked diagonal
// tiles are skipped per row-tile (wave-uniform doA/doB). Grid = 64 bh x 4 = 256 blocks,
// balanced phase pairs (q256 = p, 7-p). LDS 64 KiB (Kv 32K + Ps 8x4K).
__global__ __launch_bounds__(512, 2) void attn_causal(const unsigned short* __restrict__ Q,
                                                      const unsigned short* __restrict__ Km,
                                                      const unsigned short* __restrict__ Vt,
                                                      unsigned short* __restrict__ O) {
  __shared__ __align__(16) unsigned short Kv[2][2][64 * 64];  // [buf][K=0/V=1], unpadded
  __shared__ __align__(16) unsigned short Ps[8][2048];        // per-wave P_A | P_B, swizzled

  const int bid = blockIdx.x;
  const int xcd = bid & 7, g = bid >> 3;  // grid 256 = 8 XCDs x 32
  const int p = g >> 3;                   // 256-row chunk pair index 0..3
  const int bh = xcd * 8 + (g & 7);       // all 4 blocks of one (b,h) share XCD 'xcd'
  const int h = bh & 15;
  const int b = bh >> 4;

  const int t = threadIdx.x;
  const int wave = t >> 6, lane = t & 63;
  const int lr = lane & 15, quad = lane >> 4;
  const int cxor = lr & 7;

  const size_t base = (size_t)b * SEQ * D_MODEL + h * HEAD_DIM;
  const unsigned short* Qb = Q + base;
  const unsigned short* Kb = Km + base;
  const unsigned short* Vb = Vt + (size_t)(b * N_HEADS + h) * HEAD_DIM * SEQ;
  unsigned short* pwA = &Ps[wave][0];
  unsigned short* pwB = &Ps[wave][1024];

  const int srow = t >> 3;
  const int scol = ((t & 7) ^ (srow & 7)) << 3;
  const unsigned short* Kg = Kb + (size_t)srow * D_MODEL + scol;
  const unsigned short* Vg = Vb + (size_t)srow * SEQ + scol;

  for (int ph = 0; ph < 2; ph++) {
    const int q256 = ph ? (7 - p) : p;
    const int m0A = q256 * 256 + wave * 16;
    const int m0B = m0A + 128;
    const int nt = (q256 + 1) * 4;

    bf16x8 qfA[2], qfB[2];
#pragma unroll
    for (int kk = 0; kk < 2; kk++) {
      qfA[kk] = __builtin_bit_cast(
          bf16x8,
          *reinterpret_cast<const short8*>(Qb + (size_t)(m0A + lr) * D_MODEL + kk * 32 + quad * 8));
      qfB[kk] = __builtin_bit_cast(
          bf16x8,
          *reinterpret_cast<const short8*>(Qb + (size_t)(m0B + lr) * D_MODEL + kk * 32 + quad * 8));
    }

    f32x4 oA[4] = {}, oB[4] = {};
    float lsA = 0.f, lsB = 0.f;

    gl_lds16(Kg, &Kv[0][0][t * 8]);
    gl_lds16(Vg, &Kv[0][1][t * 8]);

    for (int kt = 0; kt < nt; kt++) {
      const int cur = kt & 1;
      const int kv0 = kt * 64;
      __syncthreads();  // drains gl_lds into buf[cur]; orders buf[1-cur] reuse
      if (kt + 1 < nt) {
        gl_lds16(Kg + (size_t)(kv0 + 64) * D_MODEL, &Kv[1 - cur][0][t * 8]);
        gl_lds16(Vg + kv0 + 64, &Kv[1 - cur][1][t * 8]);
      }
      const unsigned short* Ks = &Kv[cur][0][0];
      const unsigned short* Vs = &Kv[cur][1][0];

      // wave-uniform: row-tile active iff it has any unmasked row for this kv tile
      const bool doA = (kv0 <= m0A + 15);
      const bool doB = (kv0 <= m0B + 15);

      // S^T: s*[j][r] = S[k = kv0+16j+4*quad+r][q = m0*+lr]; kf read ONCE for both tiles
      f32x4 sA[4] = {}, sB[4] = {};
      __builtin_amdgcn_s_setprio(1);
#pragma unroll
      for (int kk = 0; kk < 2; kk++) {
        bf16x8 kf[4];
#pragma unroll
        for (int j = 0; j < 4; j++)
          kf[j] = __builtin_bit_cast(
              bf16x8, *reinterpret_cast<const short8*>(
                          &Ks[(j * 16 + lr) * 64 + ((kk * 4 + quad) ^ cxor) * 8]));
        if (doA) {
#pragma unroll
          for (int j = 0; j < 4; j++)
            sA[j] = __builtin_amdgcn_mfma_f32_16x16x32_bf16(kf[j], qfA[kk], sA[j], 0, 0, 0);
        }
        if (doB) {
#pragma unroll
          for (int j = 0; j < 4; j++)
            sB[j] = __builtin_amdgcn_mfma_f32_16x16x32_bf16(kf[j], qfB[kk], sB[j], 0, 0, 0);
        }
      }
      __builtin_amdgcn_s_setprio(0);

      WAIT_LGKM0();  // prev tile's pf reads drained before overwriting Ps

      auto softmax_store = [&](const f32x4* s, int m0, unsigned short* pw, float& lsum) {
        const bool needmask = (kv0 + 63 > m0);  // wave-uniform
        const int kbase = kv0 - m0 + quad * 4;
#pragma unroll
        for (int j = 0; j < 4; j++) {
          float e[4];
#pragma unroll
          for (int r = 0; r < 4; r++) e[r] = EXP2F(s[j][r]);
          if (needmask) {
#pragma unroll
            for (int r = 0; r < 4; r++)
              if (kbase + 16 * j + r > lr) e[r] = 0.f;
          }
          lsum += (e[0] + e[1]) + (e[2] + e[3]);
          const unsigned int pk0 = cvtpk_bf16(e[0], e[1]);
          const unsigned int pk1 = cvtpk_bf16(e[2], e[3]);
          const int c = 4 * j + quad;  // 8B-granule index along k
          *reinterpret_cast<uint2*>(
              &pw[lr * 64 + (((c >> 1) ^ (lr & 7)) << 3) + ((c & 1) << 2)]) =
              make_uint2(pk0, pk1);
        }
      };
      if (doA) softmax_store(sA, m0A, pwA, lsA);
      if (doB) softmax_store(sB, m0B, pwB, lsB);

      WAIT_LGKM0();  // P writes visible (same-wave RAW)

      __builtin_amdgcn_s_setprio(1);
#pragma unroll
      for (int kk = 0; kk < 2; kk++) {
        bf16x8 pfA = {}, pfB = {};
        if (doA)
          pfA = __builtin_bit_cast(
              bf16x8, *reinterpret_cast<const short8*>(
                          &pwA[lr * 64 + (((kk * 4 + quad) ^ (lr & 7)) << 3)]));
        if (doB)
          pfB = __builtin_bit_cast(
              bf16x8, *reinterpret_cast<const short8*>(
                          &pwB[lr * 64 + (((kk * 4 + quad) ^ (lr & 7)) << 3)]));
#pragma unroll
        for (int c = 0; c < 4; c++) {
          bf16x8 vv = __builtin_bit_cast(
              bf16x8, *reinterpret_cast<const short8*>(
                          &Vs[(c * 16 + lr) * 64 + ((kk * 4 + quad) ^ cxor) * 8]));
          if (doA) oA[c] = __builtin_amdgcn_mfma_f32_16x16x32_bf16(pfA, vv, oA[c], 0, 0, 0);
          if (doB) oB[c] = __builtin_amdgcn_mfma_f32_16x16x32_bf16(pfB, vv, oB[c], 0, 0, 0);
        }
      }
      __builtin_amdgcn_s_setprio(0);
    }

    // denominators + O writes for both row-tiles
    auto finish = [&](float lsum, const f32x4* o, int m0) {
      float l = lsum;
      l += __shfl_xor(l, 16, 64);
      l += __shfl_xor(l, 32, 64);  // every lane: full denom for q = m0 + lr
#pragma unroll
      for (int r = 0; r < 4; r++) {
        const float lq = __shfl(l, quad * 4 + r, 16);  // denom for q = m0 + quad*4 + r
        const float inv = 1.f / lq;
        const int qpos = m0 + quad * 4 + r;
#pragma unroll
        for (int c = 0; c < 4; c++)
          O[base + (size_t)qpos * D_MODEL + c * 16 + lr] = f2bf_rne(o[c][r] * inv);
      }
    };
    finish(lsA, oA, m0A);
    finish(lsB, oB, m0B);
  }
}

// ---------------- launch ----------------
extern "C" void kernel_launch(void* const* d_in, const int* in_sizes, int n_in,
                              void* d_out, int out_size, void* d_ws, size_t ws_size,
                              hipStream_t stream) {
  const float* x  = (const float*)d_in[0];
  const float* Wq = (const float*)d_in[1];
  const float* Wk = (const float*)d_in[2];
  const float* Wv = (const float*)d_in[3];
  const float* Wo = (const float*)d_in[4];
  float* out = (float*)d_out;

  char* ws = (char*)d_ws;
  const size_t SZ_X = (size_t)M_ROWS * D_MODEL * 2;   // 16 MB
  const size_t SZ_W = (size_t)D_MODEL * D_MODEL * 2;  //  2 MB
  unsigned short* xb  = (unsigned short*)(ws);
  unsigned short* wqb = (unsigned short*)(ws + SZ_X);
  unsigned short* wkb = (unsigned short*)(ws + SZ_X + 1 * SZ_W);
  unsigned short* wvb = (unsigned short*)(ws + SZ_X + 2 * SZ_W);
  unsigned short* wob = (unsigned short*)(ws + SZ_X + 3 * SZ_W);
  unsigned short* Qb  = (unsigned short*)(ws + 1 * SZ_X + 4 * SZ_W);
  unsigned short* Kb  = (unsigned short*)(ws + 2 * SZ_X + 4 * SZ_W);
  unsigned short* Vt  = (unsigned short*)(ws + 3 * SZ_X + 4 * SZ_W);
  unsigned short* Ob  = xb;  // x dead after QKV projection

  cvt_all<<<12288, 256, 0, stream>>>(x, Wq, Wk, Wv, Wo, xb, wqb, wkb, wvb, wob);

  qk_gemm8<<<256, 512, 0, stream>>>(xb, wqb, wkb, Qb, Kb);

  v_gemm<<<dim3(8, 64), 256, 0, stream>>>(xb, wvb, Vt);

  attn_causal<<<256, 512, 0, stream>>>(Qb, Kb, Vt, Ob);

  gemm_bt_f32<<<dim3(8, 64), 256, 0, stream>>>(Ob, wob, out, M_ROWS, D_MODEL, D_MODEL);
}

// Round 12
// 247.216 us; speedup vs baseline: 1.0269x; 1.0269x over previous
//
#include <hip/hip_runtime.h>
#include <hip/hip_bf16.h>

#define D_MODEL 1024
#define N_HEADS 16
#define HEAD_DIM 64
#define BATCH 4
#define SEQ 2048
#define M_ROWS (BATCH * SEQ)  // 8192

typedef __attribute__((ext_vector_type(8))) __bf16 bf16x8;
typedef __attribute__((ext_vector_type(8))) short short8;
typedef __attribute__((ext_vector_type(4))) float f32x4;

static __device__ __forceinline__ unsigned short f2bf_rne(float f) {
  unsigned int u = __float_as_uint(f);
  u += 0x7FFFu + ((u >> 16) & 1u);
  return (unsigned short)(u >> 16);
}

// pack two f32 -> two bf16 (RNE) in one instruction; no builtin on gfx950 (T12 recipe)
static __device__ __forceinline__ unsigned int cvtpk_bf16(float a, float b) {
  unsigned int r;
  asm("v_cvt_pk_bf16_f32 %0, %1, %2" : "=v"(r) : "v"(a), "v"(b));
  return r;
}

#if __has_builtin(__builtin_amdgcn_exp2f)
#define EXP2F(x) __builtin_amdgcn_exp2f(x)
#else
#define EXP2F(x) exp2f(x)
#endif

static __device__ __forceinline__ void gl_lds16(const unsigned short* g, unsigned short* l) {
  __builtin_amdgcn_global_load_lds((const __attribute__((address_space(1))) unsigned int*)g,
                                   (__attribute__((address_space(3))) unsigned int*)l, 16, 0, 0);
}

// raw barrier (no vmcnt(0) drain!) + compiler memory fence
#define BAR() asm volatile("s_barrier" ::: "memory")
#define WAIT_LGKM0() asm volatile("s_waitcnt lgkmcnt(0)" ::: "memory")
#define WAIT_VM(N) asm volatile("s_waitcnt vmcnt(" #N ")" ::: "memory")

// ---------------- merged fp32 -> bf16 conversion (x + 4 weights), one launch ----------------
__global__ __launch_bounds__(256) void cvt_all(const float* __restrict__ x,
                                               const float* __restrict__ wq,
                                               const float* __restrict__ wk,
                                               const float* __restrict__ wv,
                                               const float* __restrict__ wo,
                                               unsigned short* __restrict__ xb,
                                               unsigned short* __restrict__ wqb,
                                               unsigned short* __restrict__ wkb,
                                               unsigned short* __restrict__ wvb,
                                               unsigned short* __restrict__ wob) {
  const int bid = blockIdx.x;
  const float* src;
  unsigned short* dst;
  int i;
  if (bid < 8192) {
    src = x; dst = xb; i = bid * 256 + threadIdx.x;
  } else {
    int r = bid - 8192;
    int w = r >> 10;
    i = (r & 1023) * 256 + threadIdx.x;
    switch (w) {
      case 0: src = wq; dst = wqb; break;
      case 1: src = wk; dst = wkb; break;
      case 2: src = wv; dst = wvb; break;
      default: src = wo; dst = wob; break;
    }
  }
  float4 f = reinterpret_cast<const float4*>(src)[i];
  ushort4 o;
  o.x = f2bf_rne(f.x); o.y = f2bf_rne(f.y); o.z = f2bf_rne(f.z); o.w = f2bf_rne(f.w);
  reinterpret_cast<ushort4*>(dst)[i] = o;
}

// ---------------- Q+K GEMM: 256x256 tile, 8-phase counted-vmcnt schedule (m201) ------------
// Grid = 2 weights x 32 x 4 = 256 blocks = EXACTLY 1 round at 1 block/CU (128 KiB LDS).
__global__ __launch_bounds__(512, 2) void qk_gemm8(const unsigned short* __restrict__ A,
                                                   const unsigned short* __restrict__ Wq,
                                                   const unsigned short* __restrict__ Wk,
                                                   unsigned short* __restrict__ Qo,
                                                   unsigned short* __restrict__ Ko) {
  // layout (ushort units): A: [buf][half] 4 x 8192 at 0; B: 4 x 8192 at 32768. 128 KiB total.
  __shared__ __align__(16) unsigned short smem[65536];

  const int bid = blockIdx.x;
  const int wgid = (bid & 7) * 32 + (bid >> 3);  // XCD-chunked, bijective (256 = 8*32)
  const int widx = wgid >> 7;                    // 0=Q 1=K
  const int rem = wgid & 127;
  const int bm = rem >> 2, bn = rem & 3;

  const unsigned short* Bw = (widx == 0) ? Wq : Wk;

  const int t = threadIdx.x;
  const int wave = t >> 6, lane = t & 63;
  const int wmi = wave >> 2, wni = wave & 3;  // 2 x 4 wave grid
  const int lr = lane & 15, quad = lane >> 4;

  // staging slots: slot s in [0,1024) -> LDS linear s*16B; row r=s>>3, src chunk=(s&7)^(r&7)
  const int r0 = t >> 3, c0 = (t & 7) ^ (r0 & 7);
  const int s1 = t + 512;
  const int r1 = s1 >> 3, c1 = (s1 & 7) ^ (r1 & 7);
  const unsigned short* Asrc0 = A + (size_t)(bm * 256 + r0) * D_MODEL + c0 * 8;
  const unsigned short* Asrc1 = A + (size_t)(bm * 256 + r1) * D_MODEL + c1 * 8;
  const unsigned short* Bsrc0 = Bw + (size_t)(bn * 256 + r0) * D_MODEL + c0 * 8;
  const unsigned short* Bsrc1 = Bw + (size_t)(bn * 256 + r1) * D_MODEL + c1 * 8;

  auto stageA = [&](int kt, int buf, int half) {
    unsigned short* dst = &smem[(buf * 2 + half) * 8192];
    const size_t go = (size_t)half * (128 * D_MODEL) + kt * 64;
    gl_lds16(Asrc0 + go, dst + t * 8);
    gl_lds16(Asrc1 + go, dst + s1 * 8);
  };
  auto stageB = [&](int kt, int buf, int half) {
    unsigned short* dst = &smem[32768 + (buf * 2 + half) * 8192];
    const size_t go = (size_t)half * (128 * D_MODEL) + kt * 64;
    gl_lds16(Bsrc0 + go, dst + t * 8);
    gl_lds16(Bsrc1 + go, dst + s1 * 8);
  };

  f32x4 acc[8][4] = {};
  bf16x8 bfrag[4][2];

  // prologue: A(0),B(0) -> buf0 ; B(1) -> buf1 ; A(1) staged at iter0 p0/p1
  stageA(0, 0, 0); stageA(0, 0, 1);
  stageB(0, 0, 0); stageB(0, 0, 1);
  stageB(1, 1, 0); stageB(1, 1, 1);
  WAIT_VM(4);  // drain A(0)+B(0) (8 oldest); B(1) stays in flight
  BAR();

  const int brow0 = (wni & 1) * 64;
  for (int j = 0; j < 8; ++j) {
#pragma unroll
    for (int tb = 0; tb < 2; ++tb) {
      const unsigned short* As = &smem[(tb * 2 + wmi) * 8192];
      const unsigned short* Bs = &smem[32768 + (tb * 2 + (wni >> 1)) * 8192];
#pragma unroll
      for (int qd = 0; qd < 4; ++qd) {
        const int p = tb * 4 + qd;
        if (qd == 0) {  // whole-K-tile B fragments, kept in regs for 4 phases
#pragma unroll
          for (int n = 0; n < 4; ++n)
#pragma unroll
            for (int ks = 0; ks < 2; ++ks) {
              const int row = brow0 + n * 16 + lr;
              bfrag[n][ks] = __builtin_bit_cast(
                  bf16x8, *reinterpret_cast<const short8*>(
                              &Bs[row * 64 + (((ks * 4 + quad) ^ (row & 7)) * 8)]));
            }
        }
        bf16x8 af[2][2];
#pragma unroll
        for (int mi = 0; mi < 2; ++mi)
#pragma unroll
          for (int ks = 0; ks < 2; ++ks) {
            const int row = (qd * 2 + mi) * 16 + lr;
            af[mi][ks] = __builtin_bit_cast(
                bf16x8, *reinterpret_cast<const short8*>(
                            &As[row * 64 + (((ks * 4 + quad) ^ (row & 7)) * 8)]));
          }
        // stage schedule: each target buffer freed (all waves' reads done + barrier) before issue
        if (p == 0) stageA(2 * j + 1, 1, 0);
        if (p == 1) { stageA(2 * j + 1, 1, 1); if (j < 7) stageB(2 * j + 2, 0, 0); }
        if (p == 2) { if (j < 7) stageB(2 * j + 2, 0, 1); }
        if (p == 4) { if (j < 7) stageA(2 * j + 2, 0, 0); }
        if (p == 5) { if (j < 7) { stageA(2 * j + 2, 0, 1); stageB(2 * j + 3, 1, 0); } }
        if (p == 6) { if (j < 7) stageB(2 * j + 3, 1, 1); }
        BAR();
        WAIT_LGKM0();
        __builtin_amdgcn_s_setprio(1);
#pragma unroll
        for (int mi = 0; mi < 2; ++mi)
#pragma unroll
          for (int n = 0; n < 4; ++n)
#pragma unroll
            for (int ks = 0; ks < 2; ++ks)
              acc[qd * 2 + mi][n] = __builtin_amdgcn_mfma_f32_16x16x32_bf16(
                  af[mi][ks], bfrag[n][ks], acc[qd * 2 + mi][n], 0, 0, 0);
        __builtin_amdgcn_s_setprio(0);
        // counted waits, FIFO drain: p3 ensures tile 2j+1 (buf1) landed, p7 ensures 2j+2 (buf0)
        if (p == 3) { if (j < 7) { WAIT_VM(4); } else { WAIT_VM(0); } }
        if (p == 7) { if (j < 7) { WAIT_VM(4); } }
        BAR();
      }
    }
  }

  unsigned short* Cp = (widx == 0) ? Qo : Ko;
  const float sc = (widx == 0) ? 0.18033688f : 1.0f;  // Q: 1/8 * log2(e)
#pragma unroll
  for (int m = 0; m < 8; ++m) {
#pragma unroll
    for (int n = 0; n < 4; ++n) {
      const int col = bn * 256 + wni * 64 + n * 16 + lr;
#pragma unroll
      for (int r = 0; r < 4; ++r) {
        const int row = bm * 256 + wmi * 128 + m * 16 + quad * 4 + r;
        Cp[(size_t)row * D_MODEL + col] = f2bf_rne(acc[m][n][r] * sc);
      }
    }
  }
}

// ---------------- V GEMM: 128x128 tile, dbuf + XOR swizzle + transpose epilogue -----------
__global__ __launch_bounds__(256) void v_gemm(const unsigned short* __restrict__ A,
                                              const unsigned short* __restrict__ Bw,
                                              unsigned short* __restrict__ Vt) {
  __shared__ __align__(16) unsigned short smem[16384];
  const int t = threadIdx.x;
  const int bn = blockIdx.x, bm = blockIdx.y;
  const int K = D_MODEL;
  const int wave = t >> 6, lane = t & 63;
  const int wm = (wave >> 1) * 64, wn = (wave & 1) * 64;
  const int lr = lane & 15, quad = lane >> 4;
  const int rxor = (lr >> 1) & 3;

  const int g0 = wave * 128 + lane, g1 = g0 + 64;
  const int r0 = g0 >> 2, c0 = (((g0 & 3) ^ ((r0 >> 1) & 3)) << 3);
  const int r1 = g1 >> 2, c1 = (((g1 & 3) ^ ((r1 >> 1) & 3)) << 3);
  const unsigned short* Arow0 = A + (size_t)(bm * 128 + r0) * K + c0;
  const unsigned short* Arow1 = A + (size_t)(bm * 128 + r1) * K + c1;
  const unsigned short* Brow0 = Bw + (size_t)(bn * 128 + r0) * K + c0;
  const unsigned short* Brow1 = Bw + (size_t)(bn * 128 + r1) * K + c1;

  f32x4 acc[4][4] = {};

  gl_lds16(Arow0, &smem[g0 * 8]);
  gl_lds16(Arow1, &smem[g1 * 8]);
  gl_lds16(Brow0, &smem[4096 + g0 * 8]);
  gl_lds16(Brow1, &smem[4096 + g1 * 8]);
  __syncthreads();

  for (int it = 0; it < 32; it++) {
    const int cur = (it & 1) * 8192;
    if (it + 1 < 32) {
      const int nxt = 8192 - cur;
      const int k1 = (it + 1) * 32;
      gl_lds16(Arow0 + k1, &smem[nxt + g0 * 8]);
      gl_lds16(Arow1 + k1, &smem[nxt + g1 * 8]);
      gl_lds16(Brow0 + k1, &smem[nxt + 4096 + g0 * 8]);
      gl_lds16(Brow1 + k1, &smem[nxt + 4096 + g1 * 8]);
    }
    const unsigned short* As = &smem[cur];
    const unsigned short* Bs = &smem[cur + 4096];

    bf16x8 af[4], bfr[4];
#pragma unroll
    for (int mt = 0; mt < 4; mt++)
      af[mt] = __builtin_bit_cast(
          bf16x8,
          *reinterpret_cast<const short8*>(&As[(wm + mt * 16 + lr) * 32 + (quad ^ rxor) * 8]));
#pragma unroll
    for (int nt = 0; nt < 4; nt++)
      bfr[nt] = __builtin_bit_cast(
          bf16x8,
          *reinterpret_cast<const short8*>(&Bs[(wn + nt * 16 + lr) * 32 + (quad ^ rxor) * 8]));
#pragma unroll
    for (int mt = 0; mt < 4; mt++)
#pragma unroll
      for (int nt = 0; nt < 4; nt++)
        acc[mt][nt] = __builtin_amdgcn_mfma_f32_16x16x32_bf16(af[mt], bfr[nt], acc[mt][nt], 0, 0, 0);
    __syncthreads();
  }

  // V transpose through LDS (reuses smem), write Vt[(b*16+h2)*64+d][s]
  const int b = bm >> 4;
  const int s0 = (bm & 15) * 128;
#pragma unroll
  for (int half = 0; half < 2; half++) {
    __syncthreads();
    if ((wave & 1) == half) {
#pragma unroll
      for (int nt = 0; nt < 4; nt++) {
#pragma unroll
        for (int mt = 0; mt < 4; mt++) {
#pragma unroll
          for (int r = 0; r < 4; r++) {
            int cl = nt * 16 + lr;                 // d within this 64-col half
            int rl = wm + mt * 16 + quad * 4 + r;  // s within 128-row tile
            smem[cl * 136 + rl] = f2bf_rne(acc[mt][nt][r]);
          }
        }
      }
    }
    __syncthreads();
    const int h2 = bn * 2 + half;
    const size_t rowbase = ((size_t)(b * N_HEADS + h2)) * HEAD_DIM;
#pragma unroll
    for (int i = 0; i < 4; i++) {
      int c = i * 256 + t;
      int d = c >> 4, s8 = (c & 15) * 8;
      uint4 v = *reinterpret_cast<const uint4*>(&smem[d * 136 + s8]);
      *reinterpret_cast<uint4*>(Vt + (rowbase + d) * SEQ + s0 + s8) = v;
    }
  }
}

// ---------------- O-projection GEMM: 128x128 tile, dbuf + XOR swizzle (r13 proven) --------
__global__ __launch_bounds__(256) void gemm_bt_f32(const unsigned short* __restrict__ A,
                                                   const unsigned short* __restrict__ Bw,
                                                   float* __restrict__ Cp,
                                                   int M, int N, int K) {
  __shared__ __align__(16) unsigned short smem[16384];
  const int t = threadIdx.x;
  const int bn = blockIdx.x, bm = blockIdx.y;
  const int wave = t >> 6, lane = t & 63;
  const int wm = (wave >> 1) * 64, wn = (wave & 1) * 64;
  const int lr = lane & 15, quad = lane >> 4;
  const int rxor = (lr >> 1) & 3;

  const int g0 = wave * 128 + lane, g1 = g0 + 64;
  const int r0 = g0 >> 2, c0 = (((g0 & 3) ^ ((r0 >> 1) & 3)) << 3);
  const int r1 = g1 >> 2, c1 = (((g1 & 3) ^ ((r1 >> 1) & 3)) << 3);
  const unsigned short* Arow0 = A + (size_t)(bm * 128 + r0) * K + c0;
  const unsigned short* Arow1 = A + (size_t)(bm * 128 + r1) * K + c1;
  const unsigned short* Brow0 = Bw + (size_t)(bn * 128 + r0) * K + c0;
  const unsigned short* Brow1 = Bw + (size_t)(bn * 128 + r1) * K + c1;

  f32x4 acc[4][4] = {};

  gl_lds16(Arow0, &smem[g0 * 8]);
  gl_lds16(Arow1, &smem[g1 * 8]);
  gl_lds16(Brow0, &smem[4096 + g0 * 8]);
  gl_lds16(Brow1, &smem[4096 + g1 * 8]);
  __syncthreads();

  for (int it = 0; it < 32; it++) {
    const int cur = (it & 1) * 8192;
    if (it + 1 < 32) {
      const int nxt = 8192 - cur;
      const int k1 = (it + 1) * 32;
      gl_lds16(Arow0 + k1, &smem[nxt + g0 * 8]);
      gl_lds16(Arow1 + k1, &smem[nxt + g1 * 8]);
      gl_lds16(Brow0 + k1, &smem[nxt + 4096 + g0 * 8]);
      gl_lds16(Brow1 + k1, &smem[nxt + 4096 + g1 * 8]);
    }
    const unsigned short* As = &smem[cur];
    const unsigned short* Bs = &smem[cur + 4096];

    bf16x8 af[4], bfr[4];
#pragma unroll
    for (int mt = 0; mt < 4; mt++)
      af[mt] = __builtin_bit_cast(
          bf16x8,
          *reinterpret_cast<const short8*>(&As[(wm + mt * 16 + lr) * 32 + (quad ^ rxor) * 8]));
#pragma unroll
    for (int nt = 0; nt < 4; nt++)
      bfr[nt] = __builtin_bit_cast(
          bf16x8,
          *reinterpret_cast<const short8*>(&Bs[(wn + nt * 16 + lr) * 32 + (quad ^ rxor) * 8]));
#pragma unroll
    for (int mt = 0; mt < 4; mt++)
#pragma unroll
      for (int nt = 0; nt < 4; nt++)
        acc[mt][nt] = __builtin_amdgcn_mfma_f32_16x16x32_bf16(af[mt], bfr[nt], acc[mt][nt], 0, 0, 0);
    __syncthreads();
  }

#pragma unroll
  for (int mt = 0; mt < 4; mt++) {
#pragma unroll
    for (int nt = 0; nt < 4; nt++) {
      int col = bn * 128 + wn + nt * 16 + lr;
#pragma unroll
      for (int r = 0; r < 4; r++) {
        int row = bm * 128 + wm + mt * 16 + quad * 4 + r;
        Cp[(size_t)row * N + col] = acc[mt][nt][r];
      }
    }
  }
}

// ---------------- causal flash attention v13: 4 waves x 32 q-rows, 2 blocks/CU ------------
// v12 regressed (90us): 64KiB LDS + grid 256 forced 1 block/CU -> per-tile barrier drain
// fully exposed (latency-bound: MfmaUtil 15%, HBM 464GB/s). v13 keeps v12's 2-row-tile
// K/V LDS reuse (each kf/vv read feeds 2 MFMAs) but shrinks the block to 4 waves covering
// the SAME 128-row phase as v11: tile A rows [m0, m0+64), tile B rows [m0+64, m0+128).
// LDS 48KiB (Kv 32K + Ps 4x4K), grid 512 (v11's proven balanced qt = {p, 15-p}) -> 2
// blocks/CU co-resident restores cross-block latency hiding.
__global__ __launch_bounds__(256, 3) void attn_causal(const unsigned short* __restrict__ Q,
                                                      const unsigned short* __restrict__ Km,
                                                      const unsigned short* __restrict__ Vt,
                                                      unsigned short* __restrict__ O) {
  __shared__ __align__(16) unsigned short Kv[2][2][64 * 64];  // [buf][K=0/V=1], unpadded
  __shared__ __align__(16) unsigned short Ps[4][2048];        // per-wave P_A | P_B, swizzled

  const int bid = blockIdx.x;
  const int xcd = bid & 7, g = bid >> 3;  // grid 512 = 8 XCDs x 64
  const int p = g >> 3;                   // q-chunk pair index 0..7
  const int bh = xcd * 8 + (g & 7);       // all 8 p-blocks of one (b,h) share XCD 'xcd'
  const int h = bh & 15;
  const int b = bh >> 4;

  const int t = threadIdx.x;
  const int wave = t >> 6, lane = t & 63;  // 4 waves
  const int lr = lane & 15, quad = lane >> 4;
  const int cxor = lr & 7;

  const size_t base = (size_t)b * SEQ * D_MODEL + h * HEAD_DIM;
  const unsigned short* Qb = Q + base;
  const unsigned short* Kb = Km + base;
  const unsigned short* Vb = Vt + (size_t)(b * N_HEADS + h) * HEAD_DIM * SEQ;
  unsigned short* pwA = &Ps[wave][0];
  unsigned short* pwB = &Ps[wave][1024];

  // staging: 256 threads x 2 chunks (t, t+256); chunk c -> row c>>3, src col (c&7)^(row&7)
  const int r0 = t >> 3, c0s = (t & 7) ^ (r0 & 7);
  const int s1 = t + 256;
  const int r1 = s1 >> 3, c1s = (s1 & 7) ^ (r1 & 7);
  const unsigned short* Kg0 = Kb + (size_t)r0 * D_MODEL + c0s * 8;
  const unsigned short* Kg1 = Kb + (size_t)r1 * D_MODEL + c1s * 8;
  const unsigned short* Vg0 = Vb + (size_t)r0 * SEQ + c0s * 8;
  const unsigned short* Vg1 = Vb + (size_t)r1 * SEQ + c1s * 8;

  for (int ph = 0; ph < 2; ph++) {
    const int qt = ph ? (15 - p) : p;
    const int m0A = qt * 128 + wave * 16;  // tile A: rows [qt*128, qt*128+64)
    const int m0B = m0A + 64;              // tile B: rows [qt*128+64, qt*128+128)
    const int ntiles = (qt + 1) * 2;       // even -> phase-end stale buf is always buf0

    bf16x8 qfA[2], qfB[2];
#pragma unroll
    for (int kk = 0; kk < 2; kk++) {
      qfA[kk] = __builtin_bit_cast(
          bf16x8,
          *reinterpret_cast<const short8*>(Qb + (size_t)(m0A + lr) * D_MODEL + kk * 32 + quad * 8));
      qfB[kk] = __builtin_bit_cast(
          bf16x8,
          *reinterpret_cast<const short8*>(Qb + (size_t)(m0B + lr) * D_MODEL + kk * 32 + quad * 8));
    }

    f32x4 oA[4] = {}, oB[4] = {};
    float lsA = 0.f, lsB = 0.f;

    gl_lds16(Kg0, &Kv[0][0][t * 8]);
    gl_lds16(Kg1, &Kv[0][0][(t + 256) * 8]);
    gl_lds16(Vg0, &Kv[0][1][t * 8]);
    gl_lds16(Vg1, &Kv[0][1][(t + 256) * 8]);

    for (int kt = 0; kt < ntiles; kt++) {
      const int cur = kt & 1;
      const int kv0 = kt * 64;
      __syncthreads();  // drains gl_lds into buf[cur]; orders buf[1-cur] reuse
      if (kt + 1 < ntiles) {
        gl_lds16(Kg0 + (size_t)(kv0 + 64) * D_MODEL, &Kv[1 - cur][0][t * 8]);
        gl_lds16(Kg1 + (size_t)(kv0 + 64) * D_MODEL, &Kv[1 - cur][0][(t + 256) * 8]);
        gl_lds16(Vg0 + kv0 + 64, &Kv[1 - cur][1][t * 8]);
        gl_lds16(Vg1 + kv0 + 64, &Kv[1 - cur][1][(t + 256) * 8]);
      }
      const unsigned short* Ks = &Kv[cur][0][0];
      const unsigned short* Vs = &Kv[cur][1][0];

      // wave-uniform: row-tile active iff it has any unmasked row for this kv tile
      const bool doA = (kv0 <= m0A + 15);
      const bool doB = (kv0 <= m0B + 15);

      // S^T: s*[j][r] = S[k = kv0+16j+4*quad+r][q = m0*+lr]; kf read ONCE for both tiles
      f32x4 sA[4] = {}, sB[4] = {};
      __builtin_amdgcn_s_setprio(1);
#pragma unroll
      for (int kk = 0; kk < 2; kk++) {
        bf16x8 kf[4];
#pragma unroll
        for (int j = 0; j < 4; j++)
          kf[j] = __builtin_bit_cast(
              bf16x8, *reinterpret_cast<const short8*>(
                          &Ks[(j * 16 + lr) * 64 + ((kk * 4 + quad) ^ cxor) * 8]));
        if (doA) {
#pragma unroll
          for (int j = 0; j < 4; j++)
            sA[j] = __builtin_amdgcn_mfma_f32_16x16x32_bf16(kf[j], qfA[kk], sA[j], 0, 0, 0);
        }
        if (doB) {
#pragma unroll
          for (int j = 0; j < 4; j++)
            sB[j] = __builtin_amdgcn_mfma_f32_16x16x32_bf16(kf[j], qfB[kk], sB[j], 0, 0, 0);
        }
      }
      __builtin_amdgcn_s_setprio(0);

      WAIT_LGKM0();  // prev tile's pf reads drained before overwriting Ps

      auto softmax_store = [&](const f32x4* s, int m0, unsigned short* pw, float& lsum) {
        const bool needmask = (kv0 + 63 > m0);  // wave-uniform
        const int kbase = kv0 - m0 + quad * 4;
#pragma unroll
        for (int j = 0; j < 4; j++) {
          float e[4];
#pragma unroll
          for (int r = 0; r < 4; r++) e[r] = EXP2F(s[j][r]);
          if (needmask) {
#pragma unroll
            for (int r = 0; r < 4; r++)
              if (kbase + 16 * j + r > lr) e[r] = 0.f;
          }
          lsum += (e[0] + e[1]) + (e[2] + e[3]);
          const unsigned int pk0 = cvtpk_bf16(e[0], e[1]);
          const unsigned int pk1 = cvtpk_bf16(e[2], e[3]);
          const int c = 4 * j + quad;  // 8B-granule index along k
          *reinterpret_cast<uint2*>(
              &pw[lr * 64 + (((c >> 1) ^ (lr & 7)) << 3) + ((c & 1) << 2)]) =
              make_uint2(pk0, pk1);
        }
      };
      if (doA) softmax_store(sA, m0A, pwA, lsA);
      if (doB) softmax_store(sB, m0B, pwB, lsB);

      WAIT_LGKM0();  // P writes visible (same-wave RAW)

      __builtin_amdgcn_s_setprio(1);
#pragma unroll
      for (int kk = 0; kk < 2; kk++) {
        bf16x8 pfA = {}, pfB = {};
        if (doA)
          pfA = __builtin_bit_cast(
              bf16x8, *reinterpret_cast<const short8*>(
                          &pwA[lr * 64 + (((kk * 4 + quad) ^ (lr & 7)) << 3)]));
        if (doB)
          pfB = __builtin_bit_cast(
              bf16x8, *reinterpret_cast<const short8*>(
                          &pwB[lr * 64 + (((kk * 4 + quad) ^ (lr & 7)) << 3)]));
#pragma unroll
        for (int c = 0; c < 4; c++) {
          bf16x8 vv = __builtin_bit_cast(
              bf16x8, *reinterpret_cast<const short8*>(
                          &Vs[(c * 16 + lr) * 64 + ((kk * 4 + quad) ^ cxor) * 8]));
          if (doA) oA[c] = __builtin_amdgcn_mfma_f32_16x16x32_bf16(pfA, vv, oA[c], 0, 0, 0);
          if (doB) oB[c] = __builtin_amdgcn_mfma_f32_16x16x32_bf16(pfB, vv, oB[c], 0, 0, 0);
        }
      }
      __builtin_amdgcn_s_setprio(0);
    }

    // denominators + O writes for both row-tiles
    auto finish = [&](float lsum, const f32x4* o, int m0) {
      float l = lsum;
      l += __shfl_xor(l, 16, 64);
      l += __shfl_xor(l, 32, 64);  // every lane: full denom for q = m0 + lr
#pragma unroll
      for (int r = 0; r < 4; r++) {
        const float lq = __shfl(l, quad * 4 + r, 16);  // denom for q = m0 + quad*4 + r
        const float inv = 1.f / lq;
        const int qpos = m0 + quad * 4 + r;
#pragma unroll
        for (int c = 0; c < 4; c++)
          O[base + (size_t)qpos * D_MODEL + c * 16 + lr] = f2bf_rne(o[c][r] * inv);
      }
    };
    finish(lsA, oA, m0A);
    finish(lsB, oB, m0B);
  }
}

// ---------------- launch ----------------
extern "C" void kernel_launch(void* const* d_in, const int* in_sizes, int n_in,
                              void* d_out, int out_size, void* d_ws, size_t ws_size,
                              hipStream_t stream) {
  const float* x  = (const float*)d_in[0];
  const float* Wq = (const float*)d_in[1];
  const float* Wk = (const float*)d_in[2];
  const float* Wv = (const float*)d_in[3];
  const float* Wo = (const float*)d_in[4];
  float* out = (float*)d_out;

  char* ws = (char*)d_ws;
  const size_t SZ_X = (size_t)M_ROWS * D_MODEL * 2;   // 16 MB
  const size_t SZ_W = (size_t)D_MODEL * D_MODEL * 2;  //  2 MB
  unsigned short* xb  = (unsigned short*)(ws);
  unsigned short* wqb = (unsigned short*)(ws + SZ_X);
  unsigned short* wkb = (unsigned short*)(ws + SZ_X + 1 * SZ_W);
  unsigned short* wvb = (unsigned short*)(ws + SZ_X + 2 * SZ_W);
  unsigned short* wob = (unsigned short*)(ws + SZ_X + 3 * SZ_W);
  unsigned short* Qb  = (unsigned short*)(ws + 1 * SZ_X + 4 * SZ_W);
  unsigned short* Kb  = (unsigned short*)(ws + 2 * SZ_X + 4 * SZ_W);
  unsigned short* Vt  = (unsigned short*)(ws + 3 * SZ_X + 4 * SZ_W);
  unsigned short* Ob  = xb;  // x dead after QKV projection

  cvt_all<<<12288, 256, 0, stream>>>(x, Wq, Wk, Wv, Wo, xb, wqb, wkb, wvb, wob);

  qk_gemm8<<<256, 512, 0, stream>>>(xb, wqb, wkb, Qb, Kb);

  v_gemm<<<dim3(8, 64), 256, 0, stream>>>(xb, wvb, Vt);

  attn_causal<<<512, 256, 0, stream>>>(Qb, Kb, Vt, Ob);

  gemm_bt_f32<<<dim3(8, 64), 256, 0, stream>>>(Ob, wob, out, M_ROWS, D_MODEL, D_MODEL);
}

// Round 14
// 231.468 us; speedup vs baseline: 1.0968x; 1.0680x over previous
//
#include <hip/hip_runtime.h>
#include <hip/hip_bf16.h>

#define D_MODEL 1024
#define N_HEADS 16
#define HEAD_DIM 64
#define BATCH 4
#define SEQ 2048
#define M_ROWS (BATCH * SEQ)  // 8192

typedef __attribute__((ext_vector_type(8))) __bf16 bf16x8;
typedef __attribute__((ext_vector_type(8))) short short8;
typedef __attribute__((ext_vector_type(4))) float f32x4;

static __device__ __forceinline__ unsigned short f2bf_rne(float f) {
  unsigned int u = __float_as_uint(f);
  u += 0x7FFFu + ((u >> 16) & 1u);
  return (unsigned short)(u >> 16);
}

// pack two f32 -> two bf16 (RNE) in one instruction; no builtin on gfx950 (T12 recipe)
static __device__ __forceinline__ unsigned int cvtpk_bf16(float a, float b) {
  unsigned int r;
  asm("v_cvt_pk_bf16_f32 %0, %1, %2" : "=v"(r) : "v"(a), "v"(b));
  return r;
}

#if __has_builtin(__builtin_amdgcn_exp2f)
#define EXP2F(x) __builtin_amdgcn_exp2f(x)
#else
#define EXP2F(x) exp2f(x)
#endif

static __device__ __forceinline__ void gl_lds16(const unsigned short* g, unsigned short* l) {
  __builtin_amdgcn_global_load_lds((const __attribute__((address_space(1))) unsigned int*)g,
                                   (__attribute__((address_space(3))) unsigned int*)l, 16, 0, 0);
}

// raw barrier (no vmcnt(0) drain!) + compiler memory fence
#define BAR() asm volatile("s_barrier" ::: "memory")
#define WAIT_LGKM0() asm volatile("s_waitcnt lgkmcnt(0)" ::: "memory")
#define WAIT_VM(N) asm volatile("s_waitcnt vmcnt(" #N ")" ::: "memory")

// ---------------- merged fp32 -> bf16 conversion (x + 4 weights), one launch ----------------
__global__ __launch_bounds__(256) void cvt_all(const float* __restrict__ x,
                                               const float* __restrict__ wq,
                                               const float* __restrict__ wk,
                                               const float* __restrict__ wv,
                                               const float* __restrict__ wo,
                                               unsigned short* __restrict__ xb,
                                               unsigned short* __restrict__ wqb,
                                               unsigned short* __restrict__ wkb,
                                               unsigned short* __restrict__ wvb,
                                               unsigned short* __restrict__ wob) {
  const int bid = blockIdx.x;
  const float* src;
  unsigned short* dst;
  int i;
  if (bid < 8192) {
    src = x; dst = xb; i = bid * 256 + threadIdx.x;
  } else {
    int r = bid - 8192;
    int w = r >> 10;
    i = (r & 1023) * 256 + threadIdx.x;
    switch (w) {
      case 0: src = wq; dst = wqb; break;
      case 1: src = wk; dst = wkb; break;
      case 2: src = wv; dst = wvb; break;
      default: src = wo; dst = wob; break;
    }
  }
  float4 f = reinterpret_cast<const float4*>(src)[i];
  ushort4 o;
  o.x = f2bf_rne(f.x); o.y = f2bf_rne(f.y); o.z = f2bf_rne(f.z); o.w = f2bf_rne(f.w);
  reinterpret_cast<ushort4*>(dst)[i] = o;
}

// ---------------- Q+K GEMM: 256x256 tile, 8-phase counted-vmcnt schedule (m201) ------------
// Grid = 2 weights x 32 x 4 = 256 blocks = EXACTLY 1 round at 1 block/CU (128 KiB LDS).
__global__ __launch_bounds__(512, 2) void qk_gemm8(const unsigned short* __restrict__ A,
                                                   const unsigned short* __restrict__ Wq,
                                                   const unsigned short* __restrict__ Wk,
                                                   unsigned short* __restrict__ Qo,
                                                   unsigned short* __restrict__ Ko) {
  // layout (ushort units): A: [buf][half] 4 x 8192 at 0; B: 4 x 8192 at 32768. 128 KiB total.
  __shared__ __align__(16) unsigned short smem[65536];

  const int bid = blockIdx.x;
  const int wgid = (bid & 7) * 32 + (bid >> 3);  // XCD-chunked, bijective (256 = 8*32)
  const int widx = wgid >> 7;                    // 0=Q 1=K
  const int rem = wgid & 127;
  const int bm = rem >> 2, bn = rem & 3;

  const unsigned short* Bw = (widx == 0) ? Wq : Wk;

  const int t = threadIdx.x;
  const int wave = t >> 6, lane = t & 63;
  const int wmi = wave >> 2, wni = wave & 3;  // 2 x 4 wave grid
  const int lr = lane & 15, quad = lane >> 4;

  // staging slots: slot s in [0,1024) -> LDS linear s*16B; row r=s>>3, src chunk=(s&7)^(r&7)
  const int r0 = t >> 3, c0 = (t & 7) ^ (r0 & 7);
  const int s1 = t + 512;
  const int r1 = s1 >> 3, c1 = (s1 & 7) ^ (r1 & 7);
  const unsigned short* Asrc0 = A + (size_t)(bm * 256 + r0) * D_MODEL + c0 * 8;
  const unsigned short* Asrc1 = A + (size_t)(bm * 256 + r1) * D_MODEL + c1 * 8;
  const unsigned short* Bsrc0 = Bw + (size_t)(bn * 256 + r0) * D_MODEL + c0 * 8;
  const unsigned short* Bsrc1 = Bw + (size_t)(bn * 256 + r1) * D_MODEL + c1 * 8;

  auto stageA = [&](int kt, int buf, int half) {
    unsigned short* dst = &smem[(buf * 2 + half) * 8192];
    const size_t go = (size_t)half * (128 * D_MODEL) + kt * 64;
    gl_lds16(Asrc0 + go, dst + t * 8);
    gl_lds16(Asrc1 + go, dst + s1 * 8);
  };
  auto stageB = [&](int kt, int buf, int half) {
    unsigned short* dst = &smem[32768 + (buf * 2 + half) * 8192];
    const size_t go = (size_t)half * (128 * D_MODEL) + kt * 64;
    gl_lds16(Bsrc0 + go, dst + t * 8);
    gl_lds16(Bsrc1 + go, dst + s1 * 8);
  };

  f32x4 acc[8][4] = {};
  bf16x8 bfrag[4][2];

  // prologue: A(0),B(0) -> buf0 ; B(1) -> buf1 ; A(1) staged at iter0 p0/p1
  stageA(0, 0, 0); stageA(0, 0, 1);
  stageB(0, 0, 0); stageB(0, 0, 1);
  stageB(1, 1, 0); stageB(1, 1, 1);
  WAIT_VM(4);  // drain A(0)+B(0) (8 oldest); B(1) stays in flight
  BAR();

  const int brow0 = (wni & 1) * 64;
  for (int j = 0; j < 8; ++j) {
#pragma unroll
    for (int tb = 0; tb < 2; ++tb) {
      const unsigned short* As = &smem[(tb * 2 + wmi) * 8192];
      const unsigned short* Bs = &smem[32768 + (tb * 2 + (wni >> 1)) * 8192];
#pragma unroll
      for (int qd = 0; qd < 4; ++qd) {
        const int p = tb * 4 + qd;
        if (qd == 0) {  // whole-K-tile B fragments, kept in regs for 4 phases
#pragma unroll
          for (int n = 0; n < 4; ++n)
#pragma unroll
            for (int ks = 0; ks < 2; ++ks) {
              const int row = brow0 + n * 16 + lr;
              bfrag[n][ks] = __builtin_bit_cast(
                  bf16x8, *reinterpret_cast<const short8*>(
                              &Bs[row * 64 + (((ks * 4 + quad) ^ (row & 7)) * 8)]));
            }
        }
        bf16x8 af[2][2];
#pragma unroll
        for (int mi = 0; mi < 2; ++mi)
#pragma unroll
          for (int ks = 0; ks < 2; ++ks) {
            const int row = (qd * 2 + mi) * 16 + lr;
            af[mi][ks] = __builtin_bit_cast(
                bf16x8, *reinterpret_cast<const short8*>(
                            &As[row * 64 + (((ks * 4 + quad) ^ (row & 7)) * 8)]));
          }
        // stage schedule: each target buffer freed (all waves' reads done + barrier) before issue
        if (p == 0) stageA(2 * j + 1, 1, 0);
        if (p == 1) { stageA(2 * j + 1, 1, 1); if (j < 7) stageB(2 * j + 2, 0, 0); }
        if (p == 2) { if (j < 7) stageB(2 * j + 2, 0, 1); }
        if (p == 4) { if (j < 7) stageA(2 * j + 2, 0, 0); }
        if (p == 5) { if (j < 7) { stageA(2 * j + 2, 0, 1); stageB(2 * j + 3, 1, 0); } }
        if (p == 6) { if (j < 7) stageB(2 * j + 3, 1, 1); }
        BAR();
        WAIT_LGKM0();
        __builtin_amdgcn_s_setprio(1);
#pragma unroll
        for (int mi = 0; mi < 2; ++mi)
#pragma unroll
          for (int n = 0; n < 4; ++n)
#pragma unroll
            for (int ks = 0; ks < 2; ++ks)
              acc[qd * 2 + mi][n] = __builtin_amdgcn_mfma_f32_16x16x32_bf16(
                  af[mi][ks], bfrag[n][ks], acc[qd * 2 + mi][n], 0, 0, 0);
        __builtin_amdgcn_s_setprio(0);
        // counted waits, FIFO drain: p3 ensures tile 2j+1 (buf1) landed, p7 ensures 2j+2 (buf0)
        if (p == 3) { if (j < 7) { WAIT_VM(4); } else { WAIT_VM(0); } }
        if (p == 7) { if (j < 7) { WAIT_VM(4); } }
        BAR();
      }
    }
  }

  unsigned short* Cp = (widx == 0) ? Qo : Ko;
  const float sc = (widx == 0) ? 0.18033688f : 1.0f;  // Q: 1/8 * log2(e)
#pragma unroll
  for (int m = 0; m < 8; ++m) {
#pragma unroll
    for (int n = 0; n < 4; ++n) {
      const int col = bn * 256 + wni * 64 + n * 16 + lr;
#pragma unroll
      for (int r = 0; r < 4; ++r) {
        const int row = bm * 256 + wmi * 128 + m * 16 + quad * 4 + r;
        Cp[(size_t)row * D_MODEL + col] = f2bf_rne(acc[m][n][r] * sc);
      }
    }
  }
}

// ---------------- V GEMM: 128x128 tile, dbuf + XOR swizzle + transpose epilogue -----------
__global__ __launch_bounds__(256) void v_gemm(const unsigned short* __restrict__ A,
                                              const unsigned short* __restrict__ Bw,
                                              unsigned short* __restrict__ Vt) {
  __shared__ __align__(16) unsigned short smem[16384];
  const int t = threadIdx.x;
  const int bn = blockIdx.x, bm = blockIdx.y;
  const int K = D_MODEL;
  const int wave = t >> 6, lane = t & 63;
  const int wm = (wave >> 1) * 64, wn = (wave & 1) * 64;
  const int lr = lane & 15, quad = lane >> 4;
  const int rxor = (lr >> 1) & 3;

  const int g0 = wave * 128 + lane, g1 = g0 + 64;
  const int r0 = g0 >> 2, c0 = (((g0 & 3) ^ ((r0 >> 1) & 3)) << 3);
  const int r1 = g1 >> 2, c1 = (((g1 & 3) ^ ((r1 >> 1) & 3)) << 3);
  const unsigned short* Arow0 = A + (size_t)(bm * 128 + r0) * K + c0;
  const unsigned short* Arow1 = A + (size_t)(bm * 128 + r1) * K + c1;
  const unsigned short* Brow0 = Bw + (size_t)(bn * 128 + r0) * K + c0;
  const unsigned short* Brow1 = Bw + (size_t)(bn * 128 + r1) * K + c1;

  f32x4 acc[4][4] = {};

  gl_lds16(Arow0, &smem[g0 * 8]);
  gl_lds16(Arow1, &smem[g1 * 8]);
  gl_lds16(Brow0, &smem[4096 + g0 * 8]);
  gl_lds16(Brow1, &smem[4096 + g1 * 8]);
  __syncthreads();

  for (int it = 0; it < 32; it++) {
    const int cur = (it & 1) * 8192;
    if (it + 1 < 32) {
      const int nxt = 8192 - cur;
      const int k1 = (it + 1) * 32;
      gl_lds16(Arow0 + k1, &smem[nxt + g0 * 8]);
      gl_lds16(Arow1 + k1, &smem[nxt + g1 * 8]);
      gl_lds16(Brow0 + k1, &smem[nxt + 4096 + g0 * 8]);
      gl_lds16(Brow1 + k1, &smem[nxt + 4096 + g1 * 8]);
    }
    const unsigned short* As = &smem[cur];
    const unsigned short* Bs = &smem[cur + 4096];

    bf16x8 af[4], bfr[4];
#pragma unroll
    for (int mt = 0; mt < 4; mt++)
      af[mt] = __builtin_bit_cast(
          bf16x8,
          *reinterpret_cast<const short8*>(&As[(wm + mt * 16 + lr) * 32 + (quad ^ rxor) * 8]));
#pragma unroll
    for (int nt = 0; nt < 4; nt++)
      bfr[nt] = __builtin_bit_cast(
          bf16x8,
          *reinterpret_cast<const short8*>(&Bs[(wn + nt * 16 + lr) * 32 + (quad ^ rxor) * 8]));
#pragma unroll
    for (int mt = 0; mt < 4; mt++)
#pragma unroll
      for (int nt = 0; nt < 4; nt++)
        acc[mt][nt] = __builtin_amdgcn_mfma_f32_16x16x32_bf16(af[mt], bfr[nt], acc[mt][nt], 0, 0, 0);
    __syncthreads();
  }

  // V transpose through LDS (reuses smem), write Vt[(b*16+h2)*64+d][s]
  const int b = bm >> 4;
  const int s0 = (bm & 15) * 128;
#pragma unroll
  for (int half = 0; half < 2; half++) {
    __syncthreads();
    if ((wave & 1) == half) {
#pragma unroll
      for (int nt = 0; nt < 4; nt++) {
#pragma unroll
        for (int mt = 0; mt < 4; mt++) {
#pragma unroll
          for (int r = 0; r < 4; r++) {
            int cl = nt * 16 + lr;                 // d within this 64-col half
            int rl = wm + mt * 16 + quad * 4 + r;  // s within 128-row tile
            smem[cl * 136 + rl] = f2bf_rne(acc[mt][nt][r]);
          }
        }
      }
    }
    __syncthreads();
    const int h2 = bn * 2 + half;
    const size_t rowbase = ((size_t)(b * N_HEADS + h2)) * HEAD_DIM;
#pragma unroll
    for (int i = 0; i < 4; i++) {
      int c = i * 256 + t;
      int d = c >> 4, s8 = (c & 15) * 8;
      uint4 v = *reinterpret_cast<const uint4*>(&smem[d * 136 + s8]);
      *reinterpret_cast<uint4*>(Vt + (rowbase + d) * SEQ + s0 + s8) = v;
    }
  }
}

// ---------------- O-projection GEMM: 128x128 tile, dbuf + XOR swizzle (r13 proven) --------
__global__ __launch_bounds__(256) void gemm_bt_f32(const unsigned short* __restrict__ A,
                                                   const unsigned short* __restrict__ Bw,
                                                   float* __restrict__ Cp,
                                                   int M, int N, int K) {
  __shared__ __align__(16) unsigned short smem[16384];
  const int t = threadIdx.x;
  const int bn = blockIdx.x, bm = blockIdx.y;
  const int wave = t >> 6, lane = t & 63;
  const int wm = (wave >> 1) * 64, wn = (wave & 1) * 64;
  const int lr = lane & 15, quad = lane >> 4;
  const int rxor = (lr >> 1) & 3;

  const int g0 = wave * 128 + lane, g1 = g0 + 64;
  const int r0 = g0 >> 2, c0 = (((g0 & 3) ^ ((r0 >> 1) & 3)) << 3);
  const int r1 = g1 >> 2, c1 = (((g1 & 3) ^ ((r1 >> 1) & 3)) << 3);
  const unsigned short* Arow0 = A + (size_t)(bm * 128 + r0) * K + c0;
  const unsigned short* Arow1 = A + (size_t)(bm * 128 + r1) * K + c1;
  const unsigned short* Brow0 = Bw + (size_t)(bn * 128 + r0) * K + c0;
  const unsigned short* Brow1 = Bw + (size_t)(bn * 128 + r1) * K + c1;

  f32x4 acc[4][4] = {};

  gl_lds16(Arow0, &smem[g0 * 8]);
  gl_lds16(Arow1, &smem[g1 * 8]);
  gl_lds16(Brow0, &smem[4096 + g0 * 8]);
  gl_lds16(Brow1, &smem[4096 + g1 * 8]);
  __syncthreads();

  for (int it = 0; it < 32; it++) {
    const int cur = (it & 1) * 8192;
    if (it + 1 < 32) {
      const int nxt = 8192 - cur;
      const int k1 = (it + 1) * 32;
      gl_lds16(Arow0 + k1, &smem[nxt + g0 * 8]);
      gl_lds16(Arow1 + k1, &smem[nxt + g1 * 8]);
      gl_lds16(Brow0 + k1, &smem[nxt + 4096 + g0 * 8]);
      gl_lds16(Brow1 + k1, &smem[nxt + 4096 + g1 * 8]);
    }
    const unsigned short* As = &smem[cur];
    const unsigned short* Bs = &smem[cur + 4096];

    bf16x8 af[4], bfr[4];
#pragma unroll
    for (int mt = 0; mt < 4; mt++)
      af[mt] = __builtin_bit_cast(
          bf16x8,
          *reinterpret_cast<const short8*>(&As[(wm + mt * 16 + lr) * 32 + (quad ^ rxor) * 8]));
#pragma unroll
    for (int nt = 0; nt < 4; nt++)
      bfr[nt] = __builtin_bit_cast(
          bf16x8,
          *reinterpret_cast<const short8*>(&Bs[(wn + nt * 16 + lr) * 32 + (quad ^ rxor) * 8]));
#pragma unroll
    for (int mt = 0; mt < 4; mt++)
#pragma unroll
      for (int nt = 0; nt < 4; nt++)
        acc[mt][nt] = __builtin_amdgcn_mfma_f32_16x16x32_bf16(af[mt], bfr[nt], acc[mt][nt], 0, 0, 0);
    __syncthreads();
  }

#pragma unroll
  for (int mt = 0; mt < 4; mt++) {
#pragma unroll
    for (int nt = 0; nt < 4; nt++) {
      int col = bn * 128 + wn + nt * 16 + lr;
#pragma unroll
      for (int r = 0; r < 4; r++) {
        int row = bm * 128 + wm + mt * 16 + quad * 4 + r;
        Cp[(size_t)row * N + col] = acc[mt][nt][r];
      }
    }
  }
}

// ---------------- causal flash attention v14: v11 body, unpaired grid, 3 blocks/CU --------
// v12/v13 showed the binding constraint is resident-wave latency hiding, not LDS BW
// (v13: 2 waves/SIMD -> 75us; v11: 4 waves/SIMD -> 60us). v14 = v11 body verbatim, but
// one 128-row phase per block: grid 1024 = 64 bh x 16 qt. LDS 48KiB -> 3 blocks/CU
// co-resident (24 waves/CU = 6/SIMD, 1.5x v11). LPT dispatch (qt=15 first) so the long
// diagonal blocks start early; scheduler backfills short ones.
__global__ __launch_bounds__(512, 4) void attn_causal(const unsigned short* __restrict__ Q,
                                                      const unsigned short* __restrict__ Km,
                                                      const unsigned short* __restrict__ Vt,
                                                      unsigned short* __restrict__ O) {
  __shared__ __align__(16) unsigned short Kv[2][2][64 * 64];  // [buf][K=0/V=1], unpadded
  __shared__ __align__(16) unsigned short Ps[8][1024];        // per-wave P[q=0..15][k=0..63], swizzled

  const int bid = blockIdx.x;
  const int xcd = bid & 7, g = bid >> 3;  // grid 1024 = 8 XCDs x 128
  const int qt = 15 - (g >> 3);           // LPT: longest blocks (qt=15) dispatch first
  const int bh = xcd * 8 + (g & 7);       // all 16 qt-blocks of one (b,h) share XCD 'xcd'
  const int h = bh & 15;
  const int b = bh >> 4;

  const int t = threadIdx.x;
  const int wave = t >> 6, lane = t & 63;
  const int lr = lane & 15, quad = lane >> 4;
  const int cxor = lr & 7;

  const size_t base = (size_t)b * SEQ * D_MODEL + h * HEAD_DIM;
  const unsigned short* Qb = Q + base;
  const unsigned short* Kb = Km + base;
  const unsigned short* Vb = Vt + (size_t)(b * N_HEADS + h) * HEAD_DIM * SEQ;
  unsigned short* pw = &Ps[wave][0];

  const int srow = t >> 3;
  const int scol = ((t & 7) ^ (srow & 7)) << 3;
  const unsigned short* Kg = Kb + (size_t)srow * D_MODEL + scol;
  const unsigned short* Vg = Vb + (size_t)srow * SEQ + scol;

  const int m0 = qt * 128 + wave * 16;
  const int ntiles = (qt + 1) * 2;

  bf16x8 qf[2];
#pragma unroll
  for (int kk = 0; kk < 2; kk++)
    qf[kk] = __builtin_bit_cast(
        bf16x8,
        *reinterpret_cast<const short8*>(Qb + (size_t)(m0 + lr) * D_MODEL + kk * 32 + quad * 8));

  f32x4 o_acc[4] = {};
  float lsum = 0.f;

  gl_lds16(Kg, &Kv[0][0][t * 8]);
  gl_lds16(Vg, &Kv[0][1][t * 8]);

  for (int kt = 0; kt < ntiles; kt++) {
    const int cur = kt & 1;
    const int kv0 = kt * 64;
    __syncthreads();  // drains gl_lds into buf[cur]; orders buf[1-cur] reuse
    if (kt + 1 < ntiles) {
      gl_lds16(Kg + (size_t)(kv0 + 64) * D_MODEL, &Kv[1 - cur][0][t * 8]);
      gl_lds16(Vg + kv0 + 64, &Kv[1 - cur][1][t * 8]);
    }
    const unsigned short* Ks = &Kv[cur][0][0];
    const unsigned short* Vs = &Kv[cur][1][0];

    // S^T: sAcc[j][r] = S[k = kv0+16j+4*quad+r][q = m0+lr]
    f32x4 sAcc[4] = {};
    __builtin_amdgcn_s_setprio(1);
#pragma unroll
    for (int kk = 0; kk < 2; kk++) {
      bf16x8 kf[4];
#pragma unroll
      for (int j = 0; j < 4; j++)
        kf[j] = __builtin_bit_cast(
            bf16x8, *reinterpret_cast<const short8*>(
                        &Ks[(j * 16 + lr) * 64 + ((kk * 4 + quad) ^ cxor) * 8]));
#pragma unroll
      for (int j = 0; j < 4; j++)
        sAcc[j] = __builtin_amdgcn_mfma_f32_16x16x32_bf16(kf[j], qf[kk], sAcc[j], 0, 0, 0);
    }
    __builtin_amdgcn_s_setprio(0);

    WAIT_LGKM0();  // prev tile's pf reads drained before overwriting pw
    const bool needmask = (kv0 + 63 > m0);  // wave-uniform
    const int kbase = kv0 - m0 + quad * 4;  // k_abs - m0 - r offset base
#pragma unroll
    for (int j = 0; j < 4; j++) {
      float e[4];
#pragma unroll
      for (int r = 0; r < 4; r++) e[r] = EXP2F(sAcc[j][r]);
      if (needmask) {
#pragma unroll
        for (int r = 0; r < 4; r++)
          if (kbase + 16 * j + r > lr) e[r] = 0.f;
      }
      lsum += (e[0] + e[1]) + (e[2] + e[3]);
      const unsigned int pk0 = cvtpk_bf16(e[0], e[1]);
      const unsigned int pk1 = cvtpk_bf16(e[2], e[3]);
      const int c = 4 * j + quad;  // 8B-granule index along k
      *reinterpret_cast<uint2*>(
          &pw[lr * 64 + (((c >> 1) ^ (lr & 7)) << 3) + ((c & 1) << 2)]) =
          make_uint2(pk0, pk1);
    }
    WAIT_LGKM0();  // P writes visible (same-wave RAW)

    __builtin_amdgcn_s_setprio(1);
#pragma unroll
    for (int kk = 0; kk < 2; kk++) {
      bf16x8 pf = __builtin_bit_cast(
          bf16x8, *reinterpret_cast<const short8*>(
                      &pw[lr * 64 + (((kk * 4 + quad) ^ (lr & 7)) << 3)]));
#pragma unroll
      for (int c = 0; c < 4; c++) {
        bf16x8 vv = __builtin_bit_cast(
            bf16x8, *reinterpret_cast<const short8*>(
                        &Vs[(c * 16 + lr) * 64 + ((kk * 4 + quad) ^ cxor) * 8]));
        o_acc[c] = __builtin_amdgcn_mfma_f32_16x16x32_bf16(pf, vv, o_acc[c], 0, 0, 0);
      }
    }
    __builtin_amdgcn_s_setprio(0);
  }

  // lsum: lane holds partial for q=m0+lr over k in its quad slots; all-reduce over quads
  float l = lsum;
  l += __shfl_xor(l, 16, 64);
  l += __shfl_xor(l, 32, 64);  // every lane: full denom for q = m0 + lr
#pragma unroll
  for (int r = 0; r < 4; r++) {
    const float lq = __shfl(l, quad * 4 + r, 16);  // denom for q = m0 + quad*4 + r
    const float inv = 1.f / lq;
    const int qpos = m0 + quad * 4 + r;
#pragma unroll
    for (int c = 0; c < 4; c++)
      O[base + (size_t)qpos * D_MODEL + c * 16 + lr] = f2bf_rne(o_acc[c][r] * inv);
  }
}

// ---------------- launch ----------------
extern "C" void kernel_launch(void* const* d_in, const int* in_sizes, int n_in,
                              void* d_out, int out_size, void* d_ws, size_t ws_size,
                              hipStream_t stream) {
  const float* x  = (const float*)d_in[0];
  const float* Wq = (const float*)d_in[1];
  const float* Wk = (const float*)d_in[2];
  const float* Wv = (const float*)d_in[3];
  const float* Wo = (const float*)d_in[4];
  float* out = (float*)d_out;

  char* ws = (char*)d_ws;
  const size_t SZ_X = (size_t)M_ROWS * D_MODEL * 2;   // 16 MB
  const size_t SZ_W = (size_t)D_MODEL * D_MODEL * 2;  //  2 MB
  unsigned short* xb  = (unsigned short*)(ws);
  unsigned short* wqb = (unsigned short*)(ws + SZ_X);
  unsigned short* wkb = (unsigned short*)(ws + SZ_X + 1 * SZ_W);
  unsigned short* wvb = (unsigned short*)(ws + SZ_X + 2 * SZ_W);
  unsigned short* wob = (unsigned short*)(ws + SZ_X + 3 * SZ_W);
  unsigned short* Qb  = (unsigned short*)(ws + 1 * SZ_X + 4 * SZ_W);
  unsigned short* Kb  = (unsigned short*)(ws + 2 * SZ_X + 4 * SZ_W);
  unsigned short* Vt  = (unsigned short*)(ws + 3 * SZ_X + 4 * SZ_W);
  unsigned short* Ob  = xb;  // x dead after QKV projection

  cvt_all<<<12288, 256, 0, stream>>>(x, Wq, Wk, Wv, Wo, xb, wqb, wkb, wvb, wob);

  qk_gemm8<<<256, 512, 0, stream>>>(xb, wqb, wkb, Qb, Kb);

  v_gemm<<<dim3(8, 64), 256, 0, stream>>>(xb, wvb, Vt);

  attn_causal<<<1024, 512, 0, stream>>>(Qb, Kb, Vt, Ob);

  gemm_bt_f32<<<dim3(8, 64), 256, 0, stream>>>(Ob, wob, out, M_ROWS, D_MODEL, D_MODEL);
}

// Round 16
// 230.942 us; speedup vs baseline: 1.0993x; 1.0023x over previous
//
#include <hip/hip_runtime.h>
#include <hip/hip_bf16.h>

#define D_MODEL 1024
#define N_HEADS 16
#define HEAD_DIM 64
#define BATCH 4
#define SEQ 2048
#define M_ROWS (BATCH * SEQ)  // 8192

typedef __attribute__((ext_vector_type(8))) __bf16 bf16x8;
typedef __attribute__((ext_vector_type(8))) short short8;
typedef __attribute__((ext_vector_type(4))) float f32x4;

static __device__ __forceinline__ unsigned short f2bf_rne(float f) {
  unsigned int u = __float_as_uint(f);
  u += 0x7FFFu + ((u >> 16) & 1u);
  return (unsigned short)(u >> 16);
}

// pack two f32 -> two bf16 (RNE) in one instruction; no builtin on gfx950 (T12 recipe)
static __device__ __forceinline__ unsigned int cvtpk_bf16(float a, float b) {
  unsigned int r;
  asm("v_cvt_pk_bf16_f32 %0, %1, %2" : "=v"(r) : "v"(a), "v"(b));
  return r;
}

#if __has_builtin(__builtin_amdgcn_exp2f)
#define EXP2F(x) __builtin_amdgcn_exp2f(x)
#else
#define EXP2F(x) exp2f(x)
#endif

static __device__ __forceinline__ void gl_lds16(const unsigned short* g, unsigned short* l) {
  __builtin_amdgcn_global_load_lds((const __attribute__((address_space(1))) unsigned int*)g,
                                   (__attribute__((address_space(3))) unsigned int*)l, 16, 0, 0);
}

// raw barrier (no vmcnt(0) drain!) + compiler memory fence
#define BAR() asm volatile("s_barrier" ::: "memory")
#define WAIT_LGKM0() asm volatile("s_waitcnt lgkmcnt(0)" ::: "memory")
#define WAIT_VM(N) asm volatile("s_waitcnt vmcnt(" #N ")" ::: "memory")

// ---------------- merged fp32 -> bf16 conversion (x + 4 weights), one launch ----------------
__global__ __launch_bounds__(256) void cvt_all(const float* __restrict__ x,
                                               const float* __restrict__ wq,
                                               const float* __restrict__ wk,
                                               const float* __restrict__ wv,
                                               const float* __restrict__ wo,
                                               unsigned short* __restrict__ xb,
                                               unsigned short* __restrict__ wqb,
                                               unsigned short* __restrict__ wkb,
                                               unsigned short* __restrict__ wvb,
                                               unsigned short* __restrict__ wob) {
  const int bid = blockIdx.x;
  const float* src;
  unsigned short* dst;
  int i;
  if (bid < 8192) {
    src = x; dst = xb; i = bid * 256 + threadIdx.x;
  } else {
    int r = bid - 8192;
    int w = r >> 10;
    i = (r & 1023) * 256 + threadIdx.x;
    switch (w) {
      case 0: src = wq; dst = wqb; break;
      case 1: src = wk; dst = wkb; break;
      case 2: src = wv; dst = wvb; break;
      default: src = wo; dst = wob; break;
    }
  }
  float4 f = reinterpret_cast<const float4*>(src)[i];
  ushort4 o;
  o.x = f2bf_rne(f.x); o.y = f2bf_rne(f.y); o.z = f2bf_rne(f.z); o.w = f2bf_rne(f.w);
  reinterpret_cast<ushort4*>(dst)[i] = o;
}

// ---------------- Q+K GEMM: 256x256 tile, 8-phase counted-vmcnt schedule (m201) ------------
// Grid = 2 weights x 32 x 4 = 256 blocks = EXACTLY 1 round at 1 block/CU (128 KiB LDS).
__global__ __launch_bounds__(512, 2) void qk_gemm8(const unsigned short* __restrict__ A,
                                                   const unsigned short* __restrict__ Wq,
                                                   const unsigned short* __restrict__ Wk,
                                                   unsigned short* __restrict__ Qo,
                                                   unsigned short* __restrict__ Ko) {
  // layout (ushort units): A: [buf][half] 4 x 8192 at 0; B: 4 x 8192 at 32768. 128 KiB total.
  __shared__ __align__(16) unsigned short smem[65536];

  const int bid = blockIdx.x;
  const int wgid = (bid & 7) * 32 + (bid >> 3);  // XCD-chunked, bijective (256 = 8*32)
  const int widx = wgid >> 7;                    // 0=Q 1=K
  const int rem = wgid & 127;
  const int bm = rem >> 2, bn = rem & 3;

  const unsigned short* Bw = (widx == 0) ? Wq : Wk;

  const int t = threadIdx.x;
  const int wave = t >> 6, lane = t & 63;
  const int wmi = wave >> 2, wni = wave & 3;  // 2 x 4 wave grid
  const int lr = lane & 15, quad = lane >> 4;

  // staging slots: slot s in [0,1024) -> LDS linear s*16B; row r=s>>3, src chunk=(s&7)^(r&7)
  const int r0 = t >> 3, c0 = (t & 7) ^ (r0 & 7);
  const int s1 = t + 512;
  const int r1 = s1 >> 3, c1 = (s1 & 7) ^ (r1 & 7);
  const unsigned short* Asrc0 = A + (size_t)(bm * 256 + r0) * D_MODEL + c0 * 8;
  const unsigned short* Asrc1 = A + (size_t)(bm * 256 + r1) * D_MODEL + c1 * 8;
  const unsigned short* Bsrc0 = Bw + (size_t)(bn * 256 + r0) * D_MODEL + c0 * 8;
  const unsigned short* Bsrc1 = Bw + (size_t)(bn * 256 + r1) * D_MODEL + c1 * 8;

  auto stageA = [&](int kt, int buf, int half) {
    unsigned short* dst = &smem[(buf * 2 + half) * 8192];
    const size_t go = (size_t)half * (128 * D_MODEL) + kt * 64;
    gl_lds16(Asrc0 + go, dst + t * 8);
    gl_lds16(Asrc1 + go, dst + s1 * 8);
  };
  auto stageB = [&](int kt, int buf, int half) {
    unsigned short* dst = &smem[32768 + (buf * 2 + half) * 8192];
    const size_t go = (size_t)half * (128 * D_MODEL) + kt * 64;
    gl_lds16(Bsrc0 + go, dst + t * 8);
    gl_lds16(Bsrc1 + go, dst + s1 * 8);
  };

  f32x4 acc[8][4] = {};
  bf16x8 bfrag[4][2];

  // prologue: A(0),B(0) -> buf0 ; B(1) -> buf1 ; A(1) staged at iter0 p0/p1
  stageA(0, 0, 0); stageA(0, 0, 1);
  stageB(0, 0, 0); stageB(0, 0, 1);
  stageB(1, 1, 0); stageB(1, 1, 1);
  WAIT_VM(4);  // drain A(0)+B(0) (8 oldest); B(1) stays in flight
  BAR();

  const int brow0 = (wni & 1) * 64;
  for (int j = 0; j < 8; ++j) {
#pragma unroll
    for (int tb = 0; tb < 2; ++tb) {
      const unsigned short* As = &smem[(tb * 2 + wmi) * 8192];
      const unsigned short* Bs = &smem[32768 + (tb * 2 + (wni >> 1)) * 8192];
#pragma unroll
      for (int qd = 0; qd < 4; ++qd) {
        const int p = tb * 4 + qd;
        if (qd == 0) {  // whole-K-tile B fragments, kept in regs for 4 phases
#pragma unroll
          for (int n = 0; n < 4; ++n)
#pragma unroll
            for (int ks = 0; ks < 2; ++ks) {
              const int row = brow0 + n * 16 + lr;
              bfrag[n][ks] = __builtin_bit_cast(
                  bf16x8, *reinterpret_cast<const short8*>(
                              &Bs[row * 64 + (((ks * 4 + quad) ^ (row & 7)) * 8)]));
            }
        }
        bf16x8 af[2][2];
#pragma unroll
        for (int mi = 0; mi < 2; ++mi)
#pragma unroll
          for (int ks = 0; ks < 2; ++ks) {
            const int row = (qd * 2 + mi) * 16 + lr;
            af[mi][ks] = __builtin_bit_cast(
                bf16x8, *reinterpret_cast<const short8*>(
                            &As[row * 64 + (((ks * 4 + quad) ^ (row & 7)) * 8)]));
          }
        // stage schedule: each target buffer freed (all waves' reads done + barrier) before issue
        if (p == 0) stageA(2 * j + 1, 1, 0);
        if (p == 1) { stageA(2 * j + 1, 1, 1); if (j < 7) stageB(2 * j + 2, 0, 0); }
        if (p == 2) { if (j < 7) stageB(2 * j + 2, 0, 1); }
        if (p == 4) { if (j < 7) stageA(2 * j + 2, 0, 0); }
        if (p == 5) { if (j < 7) { stageA(2 * j + 2, 0, 1); stageB(2 * j + 3, 1, 0); } }
        if (p == 6) { if (j < 7) stageB(2 * j + 3, 1, 1); }
        BAR();
        WAIT_LGKM0();
        __builtin_amdgcn_s_setprio(1);
#pragma unroll
        for (int mi = 0; mi < 2; ++mi)
#pragma unroll
          for (int n = 0; n < 4; ++n)
#pragma unroll
            for (int ks = 0; ks < 2; ++ks)
              acc[qd * 2 + mi][n] = __builtin_amdgcn_mfma_f32_16x16x32_bf16(
                  af[mi][ks], bfrag[n][ks], acc[qd * 2 + mi][n], 0, 0, 0);
        __builtin_amdgcn_s_setprio(0);
        // counted waits, FIFO drain: p3 ensures tile 2j+1 (buf1) landed, p7 ensures 2j+2 (buf0)
        if (p == 3) { if (j < 7) { WAIT_VM(4); } else { WAIT_VM(0); } }
        if (p == 7) { if (j < 7) { WAIT_VM(4); } }
        BAR();
      }
    }
  }

  unsigned short* Cp = (widx == 0) ? Qo : Ko;
  const float sc = (widx == 0) ? 0.18033688f : 1.0f;  // Q: 1/8 * log2(e)
#pragma unroll
  for (int m = 0; m < 8; ++m) {
#pragma unroll
    for (int n = 0; n < 4; ++n) {
      const int col = bn * 256 + wni * 64 + n * 16 + lr;
#pragma unroll
      for (int r = 0; r < 4; ++r) {
        const int row = bm * 256 + wmi * 128 + m * 16 + quad * 4 + r;
        Cp[(size_t)row * D_MODEL + col] = f2bf_rne(acc[m][n][r] * sc);
      }
    }
  }
}

// ---------------- V GEMM: 128x128 tile, dbuf + XOR swizzle + transpose epilogue -----------
// T1: remap so the 8 blocks sharing an A-panel (same bm) land on ONE XCD's L2.
__global__ __launch_bounds__(256) void v_gemm(const unsigned short* __restrict__ A,
                                              const unsigned short* __restrict__ Bw,
                                              unsigned short* __restrict__ Vt) {
  __shared__ __align__(16) unsigned short smem[16384];
  const int t = threadIdx.x;
  const int flat = blockIdx.y * 8 + blockIdx.x;  // hw dispatch order, x fastest
  const int xcd = flat & 7, idx = flat >> 3;     // 512 = 8 * 64, bijective
  const int bm = xcd * 8 + (idx & 7);            // same-bm blocks share XCD
  const int bn = idx >> 3;
  const int K = D_MODEL;
  const int wave = t >> 6, lane = t & 63;
  const int wm = (wave >> 1) * 64, wn = (wave & 1) * 64;
  const int lr = lane & 15, quad = lane >> 4;
  const int rxor = (lr >> 1) & 3;

  const int g0 = wave * 128 + lane, g1 = g0 + 64;
  const int r0 = g0 >> 2, c0 = (((g0 & 3) ^ ((r0 >> 1) & 3)) << 3);
  const int r1 = g1 >> 2, c1 = (((g1 & 3) ^ ((r1 >> 1) & 3)) << 3);
  const unsigned short* Arow0 = A + (size_t)(bm * 128 + r0) * K + c0;
  const unsigned short* Arow1 = A + (size_t)(bm * 128 + r1) * K + c1;
  const unsigned short* Brow0 = Bw + (size_t)(bn * 128 + r0) * K + c0;
  const unsigned short* Brow1 = Bw + (size_t)(bn * 128 + r1) * K + c1;

  f32x4 acc[4][4] = {};

  gl_lds16(Arow0, &smem[g0 * 8]);
  gl_lds16(Arow1, &smem[g1 * 8]);
  gl_lds16(Brow0, &smem[4096 + g0 * 8]);
  gl_lds16(Brow1, &smem[4096 + g1 * 8]);
  __syncthreads();

  for (int it = 0; it < 32; it++) {
    const int cur = (it & 1) * 8192;
    if (it + 1 < 32) {
      const int nxt = 8192 - cur;
      const int k1 = (it + 1) * 32;
      gl_lds16(Arow0 + k1, &smem[nxt + g0 * 8]);
      gl_lds16(Arow1 + k1, &smem[nxt + g1 * 8]);
      gl_lds16(Brow0 + k1, &smem[nxt + 4096 + g0 * 8]);
      gl_lds16(Brow1 + k1, &smem[nxt + 4096 + g1 * 8]);
    }
    const unsigned short* As = &smem[cur];
    const unsigned short* Bs = &smem[cur + 4096];

    bf16x8 af[4], bfr[4];
#pragma unroll
    for (int mt = 0; mt < 4; mt++)
      af[mt] = __builtin_bit_cast(
          bf16x8,
          *reinterpret_cast<const short8*>(&As[(wm + mt * 16 + lr) * 32 + (quad ^ rxor) * 8]));
#pragma unroll
    for (int nt = 0; nt < 4; nt++)
      bfr[nt] = __builtin_bit_cast(
          bf16x8,
          *reinterpret_cast<const short8*>(&Bs[(wn + nt * 16 + lr) * 32 + (quad ^ rxor) * 8]));
#pragma unroll
    for (int mt = 0; mt < 4; mt++)
#pragma unroll
      for (int nt = 0; nt < 4; nt++)
        acc[mt][nt] = __builtin_amdgcn_mfma_f32_16x16x32_bf16(af[mt], bfr[nt], acc[mt][nt], 0, 0, 0);
    __syncthreads();
  }

  // V transpose through LDS (reuses smem), write Vt[(b*16+h2)*64+d][s]
  const int b = bm >> 4;
  const int s0 = (bm & 15) * 128;
#pragma unroll
  for (int half = 0; half < 2; half++) {
    __syncthreads();
    if ((wave & 1) == half) {
#pragma unroll
      for (int nt = 0; nt < 4; nt++) {
#pragma unroll
        for (int mt = 0; mt < 4; mt++) {
#pragma unroll
          for (int r = 0; r < 4; r++) {
            int cl = nt * 16 + lr;                 // d within this 64-col half
            int rl = wm + mt * 16 + quad * 4 + r;  // s within 128-row tile
            smem[cl * 136 + rl] = f2bf_rne(acc[mt][nt][r]);
          }
        }
      }
    }
    __syncthreads();
    const int h2 = bn * 2 + half;
    const size_t rowbase = ((size_t)(b * N_HEADS + h2)) * HEAD_DIM;
#pragma unroll
    for (int i = 0; i < 4; i++) {
      int c = i * 256 + t;
      int d = c >> 4, s8 = (c & 15) * 8;
      uint4 v = *reinterpret_cast<const uint4*>(&smem[d * 136 + s8]);
      *reinterpret_cast<uint4*>(Vt + (rowbase + d) * SEQ + s0 + s8) = v;
    }
  }
}

// ---------------- O-projection GEMM: 128x128 tile, dbuf + XOR swizzle (r13 proven) --------
// T1: same-bm blocks co-XCD (A panel L2 reuse; B weight is only 2MB, refetch is cheap).
__global__ __launch_bounds__(256) void gemm_bt_f32(const unsigned short* __restrict__ A,
                                                   const unsigned short* __restrict__ Bw,
                                                   float* __restrict__ Cp,
                                                   int M, int N, int K) {
  __shared__ __align__(16) unsigned short smem[16384];
  const int t = threadIdx.x;
  const int flat = blockIdx.y * 8 + blockIdx.x;  // hw dispatch order, x fastest
  const int xcd = flat & 7, idx = flat >> 3;     // 512 = 8 * 64, bijective
  const int bm = xcd * 8 + (idx & 7);            // same-bm blocks share XCD
  const int bn = idx >> 3;
  const int wave = t >> 6, lane = t & 63;
  const int wm = (wave >> 1) * 64, wn = (wave & 1) * 64;
  const int lr = lane & 15, quad = lane >> 4;
  const int rxor = (lr >> 1) & 3;

  const int g0 = wave * 128 + lane, g1 = g0 + 64;
  const int r0 = g0 >> 2, c0 = (((g0 & 3) ^ ((r0 >> 1) & 3)) << 3);
  const int r1 = g1 >> 2, c1 = (((g1 & 3) ^ ((r1 >> 1) & 3)) << 3);
  const unsigned short* Arow0 = A + (size_t)(bm * 128 + r0) * K + c0;
  const unsigned short* Arow1 = A + (size_t)(bm * 128 + r1) * K + c1;
  const unsigned short* Brow0 = Bw + (size_t)(bn * 128 + r0) * K + c0;
  const unsigned short* Brow1 = Bw + (size_t)(bn * 128 + r1) * K + c1;

  f32x4 acc[4][4] = {};

  gl_lds16(Arow0, &smem[g0 * 8]);
  gl_lds16(Arow1, &smem[g1 * 8]);
  gl_lds16(Brow0, &smem[4096 + g0 * 8]);
  gl_lds16(Brow1, &smem[4096 + g1 * 8]);
  __syncthreads();

  for (int it = 0; it < 32; it++) {
    const int cur = (it & 1) * 8192;
    if (it + 1 < 32) {
      const int nxt = 8192 - cur;
      const int k1 = (it + 1) * 32;
      gl_lds16(Arow0 + k1, &smem[nxt + g0 * 8]);
      gl_lds16(Arow1 + k1, &smem[nxt + g1 * 8]);
      gl_lds16(Brow0 + k1, &smem[nxt + 4096 + g0 * 8]);
      gl_lds16(Brow1 + k1, &smem[nxt + 4096 + g1 * 8]);
    }
    const unsigned short* As = &smem[cur];
    const unsigned short* Bs = &smem[cur + 4096];

    bf16x8 af[4], bfr[4];
#pragma unroll
    for (int mt = 0; mt < 4; mt++)
      af[mt] = __builtin_bit_cast(
          bf16x8,
          *reinterpret_cast<const short8*>(&As[(wm + mt * 16 + lr) * 32 + (quad ^ rxor) * 8]));
#pragma unroll
    for (int nt = 0; nt < 4; nt++)
      bfr[nt] = __builtin_bit_cast(
          bf16x8,
          *reinterpret_cast<const short8*>(&Bs[(wn + nt * 16 + lr) * 32 + (quad ^ rxor) * 8]));
#pragma unroll
    for (int mt = 0; mt < 4; mt++)
#pragma unroll
      for (int nt = 0; nt < 4; nt++)
        acc[mt][nt] = __builtin_amdgcn_mfma_f32_16x16x32_bf16(af[mt], bfr[nt], acc[mt][nt], 0, 0, 0);
    __syncthreads();
  }

#pragma unroll
  for (int mt = 0; mt < 4; mt++) {
#pragma unroll
    for (int nt = 0; nt < 4; nt++) {
      int col = bn * 128 + wn + nt * 16 + lr;
#pragma unroll
      for (int r = 0; r < 4; r++) {
        int row = bm * 128 + wm + mt * 16 + quad * 4 + r;
        Cp[(size_t)row * N + col] = acc[mt][nt][r];
      }
    }
  }
}

// ---------------- causal flash attention v15: v14 + launch_bounds(512,6) for 3 blocks/CU --
// v14 measured Occupancy ~50% (2 blocks/CU) at 56us; LDS 48KiB permits 3. Declare 6
// waves/EU (VGPR 40 << 85 ceiling, no spill risk) so the allocator/dispatcher targets
// 3 co-resident blocks = 6 waves/SIMD for deeper latency hiding of the per-tile chain.
__global__ __launch_bounds__(512, 6) void attn_causal(const unsigned short* __restrict__ Q,
                                                      const unsigned short* __restrict__ Km,
                                                      const unsigned short* __restrict__ Vt,
                                                      unsigned short* __restrict__ O) {
  __shared__ __align__(16) unsigned short Kv[2][2][64 * 64];  // [buf][K=0/V=1], unpadded
  __shared__ __align__(16) unsigned short Ps[8][1024];        // per-wave P[q=0..15][k=0..63], swizzled

  const int bid = blockIdx.x;
  const int xcd = bid & 7, g = bid >> 3;  // grid 1024 = 8 XCDs x 128
  const int qt = 15 - (g >> 3);           // LPT: longest blocks (qt=15) dispatch first
  const int bh = xcd * 8 + (g & 7);       // all 16 qt-blocks of one (b,h) share XCD 'xcd'
  const int h = bh & 15;
  const int b = bh >> 4;

  const int t = threadIdx.x;
  const int wave = t >> 6, lane = t & 63;
  const int lr = lane & 15, quad = lane >> 4;
  const int cxor = lr & 7;

  const size_t base = (size_t)b * SEQ * D_MODEL + h * HEAD_DIM;
  const unsigned short* Qb = Q + base;
  const unsigned short* Kb = Km + base;
  const unsigned short* Vb = Vt + (size_t)(b * N_HEADS + h) * HEAD_DIM * SEQ;
  unsigned short* pw = &Ps[wave][0];

  const int srow = t >> 3;
  const int scol = ((t & 7) ^ (srow & 7)) << 3;
  const unsigned short* Kg = Kb + (size_t)srow * D_MODEL + scol;
  const unsigned short* Vg = Vb + (size_t)srow * SEQ + scol;

  const int m0 = qt * 128 + wave * 16;
  const int ntiles = (qt + 1) * 2;

  bf16x8 qf[2];
#pragma unroll
  for (int kk = 0; kk < 2; kk++)
    qf[kk] = __builtin_bit_cast(
        bf16x8,
        *reinterpret_cast<const short8*>(Qb + (size_t)(m0 + lr) * D_MODEL + kk * 32 + quad * 8));

  f32x4 o_acc[4] = {};
  float lsum = 0.f;

  gl_lds16(Kg, &Kv[0][0][t * 8]);
  gl_lds16(Vg, &Kv[0][1][t * 8]);

  for (int kt = 0; kt < ntiles; kt++) {
    const int cur = kt & 1;
    const int kv0 = kt * 64;
    __syncthreads();  // drains gl_lds into buf[cur]; orders buf[1-cur] reuse
    if (kt + 1 < ntiles) {
      gl_lds16(Kg + (size_t)(kv0 + 64) * D_MODEL, &Kv[1 - cur][0][t * 8]);
      gl_lds16(Vg + kv0 + 64, &Kv[1 - cur][1][t * 8]);
    }
    const unsigned short* Ks = &Kv[cur][0][0];
    const unsigned short* Vs = &Kv[cur][1][0];

    // S^T: sAcc[j][r] = S[k = kv0+16j+4*quad+r][q = m0+lr]
    f32x4 sAcc[4] = {};
    __builtin_amdgcn_s_setprio(1);
#pragma unroll
    for (int kk = 0; kk < 2; kk++) {
      bf16x8 kf[4];
#pragma unroll
      for (int j = 0; j < 4; j++)
        kf[j] = __builtin_bit_cast(
            bf16x8, *reinterpret_cast<const short8*>(
                        &Ks[(j * 16 + lr) * 64 + ((kk * 4 + quad) ^ cxor) * 8]));
#pragma unroll
      for (int j = 0; j < 4; j++)
        sAcc[j] = __builtin_amdgcn_mfma_f32_16x16x32_bf16(kf[j], qf[kk], sAcc[j], 0, 0, 0);
    }
    __builtin_amdgcn_s_setprio(0);

    WAIT_LGKM0();  // prev tile's pf reads drained before overwriting pw
    const bool needmask = (kv0 + 63 > m0);  // wave-uniform
    const int kbase = kv0 - m0 + quad * 4;  // k_abs - m0 - r offset base
#pragma unroll
    for (int j = 0; j < 4; j++) {
      float e[4];
#pragma unroll
      for (int r = 0; r < 4; r++) e[r] = EXP2F(sAcc[j][r]);
      if (needmask) {
#pragma unroll
        for (int r = 0; r < 4; r++)
          if (kbase + 16 * j + r > lr) e[r] = 0.f;
      }
      lsum += (e[0] + e[1]) + (e[2] + e[3]);
      const unsigned int pk0 = cvtpk_bf16(e[0], e[1]);
      const unsigned int pk1 = cvtpk_bf16(e[2], e[3]);
      const int c = 4 * j + quad;  // 8B-granule index along k
      *reinterpret_cast<uint2*>(
          &pw[lr * 64 + (((c >> 1) ^ (lr & 7)) << 3) + ((c & 1) << 2)]) =
          make_uint2(pk0, pk1);
    }
    WAIT_LGKM0();  // P writes visible (same-wave RAW)

    __builtin_amdgcn_s_setprio(1);
#pragma unroll
    for (int kk = 0; kk < 2; kk++) {
      bf16x8 pf = __builtin_bit_cast(
          bf16x8, *reinterpret_cast<const short8*>(
                      &pw[lr * 64 + (((kk * 4 + quad) ^ (lr & 7)) << 3)]));
#pragma unroll
      for (int c = 0; c < 4; c++) {
        bf16x8 vv = __builtin_bit_cast(
            bf16x8, *reinterpret_cast<const short8*>(
                        &Vs[(c * 16 + lr) * 64 + ((kk * 4 + quad) ^ cxor) * 8]));
        o_acc[c] = __builtin_amdgcn_mfma_f32_16x16x32_bf16(pf, vv, o_acc[c], 0, 0, 0);
      }
    }
    __builtin_amdgcn_s_setprio(0);
  }

  // lsum: lane holds partial for q=m0+lr over k in its quad slots; all-reduce over quads
  float l = lsum;
  l += __shfl_xor(l, 16, 64);
  l += __shfl_xor(l, 32, 64);  // every lane: full denom for q = m0 + lr
#pragma unroll
  for (int r = 0; r < 4; r++) {
    const float lq = __shfl(l, quad * 4 + r, 16);  // denom for q = m0 + quad*4 + r
    const float inv = 1.f / lq;
    const int qpos = m0 + quad * 4 + r;
#pragma unroll
    for (int c = 0; c < 4; c++)
      O[base + (size_t)qpos * D_MODEL + c * 16 + lr] = f2bf_rne(o_acc[c][r] * inv);
  }
}

// ---------------- launch ----------------
extern "C" void kernel_launch(void* const* d_in, const int* in_sizes, int n_in,
                              void* d_out, int out_size, void* d_ws, size_t ws_size,
                              hipStream_t stream) {
  const float* x  = (const float*)d_in[0];
  const float* Wq = (const float*)d_in[1];
  const float* Wk = (const float*)d_in[2];
  const float* Wv = (const float*)d_in[3];
  const float* Wo = (const float*)d_in[4];
  float* out = (float*)d_out;

  char* ws = (char*)d_ws;
  const size_t SZ_X = (size_t)M_ROWS * D_MODEL * 2;   // 16 MB
  const size_t SZ_W = (size_t)D_MODEL * D_MODEL * 2;  //  2 MB
  unsigned short* xb  = (unsigned short*)(ws);
  unsigned short* wqb = (unsigned short*)(ws + SZ_X);
  unsigned short* wkb = (unsigned short*)(ws + SZ_X + 1 * SZ_W);
  unsigned short* wvb = (unsigned short*)(ws + SZ_X + 2 * SZ_W);
  unsigned short* wob = (unsigned short*)(ws + SZ_X + 3 * SZ_W);
  unsigned short* Qb  = (unsigned short*)(ws + 1 * SZ_X + 4 * SZ_W);
  unsigned short* Kb  = (unsigned short*)(ws + 2 * SZ_X + 4 * SZ_W);
  unsigned short* Vt  = (unsigned short*)(ws + 3 * SZ_X + 4 * SZ_W);
  unsigned short* Ob  = xb;  // x dead after QKV projection

  cvt_all<<<12288, 256, 0, stream>>>(x, Wq, Wk, Wv, Wo, xb, wqb, wkb, wvb, wob);

  qk_gemm8<<<256, 512, 0, stream>>>(xb, wqb, wkb, Qb, Kb);

  v_gemm<<<dim3(8, 64), 256, 0, stream>>>(xb, wvb, Vt);

  attn_causal<<<1024, 512, 0, stream>>>(Qb, Kb, Vt, Ob);

  gemm_bt_f32<<<dim3(8, 64), 256, 0, stream>>>(Ob, wob, out, M_ROWS, D_MODEL, D_MODEL);
}

// Round 19
// 228.836 us; speedup vs baseline: 1.1094x; 1.0092x over previous
//
#include <hip/hip_runtime.h>
#include <hip/hip_bf16.h>

#define D_MODEL 1024
#define N_HEADS 16
#define HEAD_DIM 64
#define BATCH 4
#define SEQ 2048
#define M_ROWS (BATCH * SEQ)  // 8192

typedef __attribute__((ext_vector_type(8))) __bf16 bf16x8;
typedef __attribute__((ext_vector_type(8))) short short8;
typedef __attribute__((ext_vector_type(4))) float f32x4;

static __device__ __forceinline__ unsigned short f2bf_rne(float f) {
  unsigned int u = __float_as_uint(f);
  u += 0x7FFFu + ((u >> 16) & 1u);
  return (unsigned short)(u >> 16);
}

// pack two f32 -> two bf16 (RNE) in one instruction; no builtin on gfx950 (T12 recipe)
static __device__ __forceinline__ unsigned int cvtpk_bf16(float a, float b) {
  unsigned int r;
  asm("v_cvt_pk_bf16_f32 %0, %1, %2" : "=v"(r) : "v"(a), "v"(b));
  return r;
}

#if __has_builtin(__builtin_amdgcn_exp2f)
#define EXP2F(x) __builtin_amdgcn_exp2f(x)
#else
#define EXP2F(x) exp2f(x)
#endif

static __device__ __forceinline__ void gl_lds16(const unsigned short* g, unsigned short* l) {
  __builtin_amdgcn_global_load_lds((const __attribute__((address_space(1))) unsigned int*)g,
                                   (__attribute__((address_space(3))) unsigned int*)l, 16, 0, 0);
}

// raw barrier (no vmcnt(0) drain!) + compiler memory fence
#define BAR() asm volatile("s_barrier" ::: "memory")
#define WAIT_LGKM0() asm volatile("s_waitcnt lgkmcnt(0)" ::: "memory")
#define WAIT_VM(N) asm volatile("s_waitcnt vmcnt(" #N ")" ::: "memory")

// ---------------- merged fp32 -> bf16 conversion (x + 4 weights), one launch ----------------
__global__ __launch_bounds__(256) void cvt_all(const float* __restrict__ x,
                                               const float* __restrict__ wq,
                                               const float* __restrict__ wk,
                                               const float* __restrict__ wv,
                                               const float* __restrict__ wo,
                                               unsigned short* __restrict__ xb,
                                               unsigned short* __restrict__ wqb,
                                               unsigned short* __restrict__ wkb,
                                               unsigned short* __restrict__ wvb,
                                               unsigned short* __restrict__ wob) {
  const int bid = blockIdx.x;
  const float* src;
  unsigned short* dst;
  int i;
  if (bid < 8192) {
    src = x; dst = xb; i = bid * 256 + threadIdx.x;
  } else {
    int r = bid - 8192;
    int w = r >> 10;
    i = (r & 1023) * 256 + threadIdx.x;
    switch (w) {
      case 0: src = wq; dst = wqb; break;
      case 1: src = wk; dst = wkb; break;
      case 2: src = wv; dst = wvb; break;
      default: src = wo; dst = wob; break;
    }
  }
  float4 f = reinterpret_cast<const float4*>(src)[i];
  ushort4 o;
  o.x = f2bf_rne(f.x); o.y = f2bf_rne(f.y); o.z = f2bf_rne(f.z); o.w = f2bf_rne(f.w);
  reinterpret_cast<ushort4*>(dst)[i] = o;
}

// ---------------- Q+K GEMM: 256x256 tile, 8-phase counted-vmcnt schedule (m201) ------------
// Grid = 2 weights x 32 x 4 = 256 blocks = EXACTLY 1 round at 1 block/CU (128 KiB LDS).
__global__ __launch_bounds__(512, 2) void qk_gemm8(const unsigned short* __restrict__ A,
                                                   const unsigned short* __restrict__ Wq,
                                                   const unsigned short* __restrict__ Wk,
                                                   unsigned short* __restrict__ Qo,
                                                   unsigned short* __restrict__ Ko) {
  // layout (ushort units): A: [buf][half] 4 x 8192 at 0; B: 4 x 8192 at 32768. 128 KiB total.
  __shared__ __align__(16) unsigned short smem[65536];

  const int bid = blockIdx.x;
  const int wgid = (bid & 7) * 32 + (bid >> 3);  // XCD-chunked, bijective (256 = 8*32)
  const int widx = wgid >> 7;                    // 0=Q 1=K
  const int rem = wgid & 127;
  const int bm = rem >> 2, bn = rem & 3;

  const unsigned short* Bw = (widx == 0) ? Wq : Wk;

  const int t = threadIdx.x;
  const int wave = t >> 6, lane = t & 63;
  const int wmi = wave >> 2, wni = wave & 3;  // 2 x 4 wave grid
  const int lr = lane & 15, quad = lane >> 4;

  // staging slots: slot s in [0,1024) -> LDS linear s*16B; row r=s>>3, src chunk=(s&7)^(r&7)
  const int r0 = t >> 3, c0 = (t & 7) ^ (r0 & 7);
  const int s1 = t + 512;
  const int r1 = s1 >> 3, c1 = (s1 & 7) ^ (r1 & 7);
  const unsigned short* Asrc0 = A + (size_t)(bm * 256 + r0) * D_MODEL + c0 * 8;
  const unsigned short* Asrc1 = A + (size_t)(bm * 256 + r1) * D_MODEL + c1 * 8;
  const unsigned short* Bsrc0 = Bw + (size_t)(bn * 256 + r0) * D_MODEL + c0 * 8;
  const unsigned short* Bsrc1 = Bw + (size_t)(bn * 256 + r1) * D_MODEL + c1 * 8;

  auto stageA = [&](int kt, int buf, int half) {
    unsigned short* dst = &smem[(buf * 2 + half) * 8192];
    const size_t go = (size_t)half * (128 * D_MODEL) + kt * 64;
    gl_lds16(Asrc0 + go, dst + t * 8);
    gl_lds16(Asrc1 + go, dst + s1 * 8);
  };
  auto stageB = [&](int kt, int buf, int half) {
    unsigned short* dst = &smem[32768 + (buf * 2 + half) * 8192];
    const size_t go = (size_t)half * (128 * D_MODEL) + kt * 64;
    gl_lds16(Bsrc0 + go, dst + t * 8);
    gl_lds16(Bsrc1 + go, dst + s1 * 8);
  };

  f32x4 acc[8][4] = {};
  bf16x8 bfrag[4][2];

  // prologue: A(0),B(0) -> buf0 ; B(1) -> buf1 ; A(1) staged at iter0 p0/p1
  stageA(0, 0, 0); stageA(0, 0, 1);
  stageB(0, 0, 0); stageB(0, 0, 1);
  stageB(1, 1, 0); stageB(1, 1, 1);
  WAIT_VM(4);  // drain A(0)+B(0) (8 oldest); B(1) stays in flight
  BAR();

  const int brow0 = (wni & 1) * 64;
  for (int j = 0; j < 8; ++j) {
#pragma unroll
    for (int tb = 0; tb < 2; ++tb) {
      const unsigned short* As = &smem[(tb * 2 + wmi) * 8192];
      const unsigned short* Bs = &smem[32768 + (tb * 2 + (wni >> 1)) * 8192];
#pragma unroll
      for (int qd = 0; qd < 4; ++qd) {
        const int p = tb * 4 + qd;
        if (qd == 0) {  // whole-K-tile B fragments, kept in regs for 4 phases
#pragma unroll
          for (int n = 0; n < 4; ++n)
#pragma unroll
            for (int ks = 0; ks < 2; ++ks) {
              const int row = brow0 + n * 16 + lr;
              bfrag[n][ks] = __builtin_bit_cast(
                  bf16x8, *reinterpret_cast<const short8*>(
                              &Bs[row * 64 + (((ks * 4 + quad) ^ (row & 7)) * 8)]));
            }
        }
        bf16x8 af[2][2];
#pragma unroll
        for (int mi = 0; mi < 2; ++mi)
#pragma unroll
          for (int ks = 0; ks < 2; ++ks) {
            const int row = (qd * 2 + mi) * 16 + lr;
            af[mi][ks] = __builtin_bit_cast(
                bf16x8, *reinterpret_cast<const short8*>(
                            &As[row * 64 + (((ks * 4 + quad) ^ (row & 7)) * 8)]));
          }
        // stage schedule: each target buffer freed (all waves' reads done + barrier) before issue
        if (p == 0) stageA(2 * j + 1, 1, 0);
        if (p == 1) { stageA(2 * j + 1, 1, 1); if (j < 7) stageB(2 * j + 2, 0, 0); }
        if (p == 2) { if (j < 7) stageB(2 * j + 2, 0, 1); }
        if (p == 4) { if (j < 7) stageA(2 * j + 2, 0, 0); }
        if (p == 5) { if (j < 7) { stageA(2 * j + 2, 0, 1); stageB(2 * j + 3, 1, 0); } }
        if (p == 6) { if (j < 7) stageB(2 * j + 3, 1, 1); }
        BAR();
        WAIT_LGKM0();
        __builtin_amdgcn_s_setprio(1);
#pragma unroll
        for (int mi = 0; mi < 2; ++mi)
#pragma unroll
          for (int n = 0; n < 4; ++n)
#pragma unroll
            for (int ks = 0; ks < 2; ++ks)
              acc[qd * 2 + mi][n] = __builtin_amdgcn_mfma_f32_16x16x32_bf16(
                  af[mi][ks], bfrag[n][ks], acc[qd * 2 + mi][n], 0, 0, 0);
        __builtin_amdgcn_s_setprio(0);
        // counted waits, FIFO drain: p3 ensures tile 2j+1 (buf1) landed, p7 ensures 2j+2 (buf0)
        if (p == 3) { if (j < 7) { WAIT_VM(4); } else { WAIT_VM(0); } }
        if (p == 7) { if (j < 7) { WAIT_VM(4); } }
        BAR();
      }
    }
  }

  unsigned short* Cp = (widx == 0) ? Qo : Ko;
  const float sc = (widx == 0) ? 0.18033688f : 1.0f;  // Q: 1/8 * log2(e)
#pragma unroll
  for (int m = 0; m < 8; ++m) {
#pragma unroll
    for (int n = 0; n < 4; ++n) {
      const int col = bn * 256 + wni * 64 + n * 16 + lr;
#pragma unroll
      for (int r = 0; r < 4; ++r) {
        const int row = bm * 256 + wmi * 128 + m * 16 + quad * 4 + r;
        Cp[(size_t)row * D_MODEL + col] = f2bf_rne(acc[m][n][r] * sc);
      }
    }
  }
}

// ---------------- V GEMM: 128x128 tile, dbuf + XOR swizzle + transpose epilogue -----------
// T1: remap so the 8 blocks sharing an A-panel (same bm) land on ONE XCD's L2.
__global__ __launch_bounds__(256) void v_gemm(const unsigned short* __restrict__ A,
                                              const unsigned short* __restrict__ Bw,
                                              unsigned short* __restrict__ Vt) {
  __shared__ __align__(16) unsigned short smem[16384];
  const int t = threadIdx.x;
  const int flat = blockIdx.y * 8 + blockIdx.x;  // hw dispatch order, x fastest
  const int xcd = flat & 7, idx = flat >> 3;     // 512 = 8 * 64, bijective
  const int bm = xcd * 8 + (idx & 7);            // same-bm blocks share XCD
  const int bn = idx >> 3;
  const int K = D_MODEL;
  const int wave = t >> 6, lane = t & 63;
  const int wm = (wave >> 1) * 64, wn = (wave & 1) * 64;
  const int lr = lane & 15, quad = lane >> 4;
  const int rxor = (lr >> 1) & 3;

  const int g0 = wave * 128 + lane, g1 = g0 + 64;
  const int r0 = g0 >> 2, c0 = (((g0 & 3) ^ ((r0 >> 1) & 3)) << 3);
  const int r1 = g1 >> 2, c1 = (((g1 & 3) ^ ((r1 >> 1) & 3)) << 3);
  const unsigned short* Arow0 = A + (size_t)(bm * 128 + r0) * K + c0;
  const unsigned short* Arow1 = A + (size_t)(bm * 128 + r1) * K + c1;
  const unsigned short* Brow0 = Bw + (size_t)(bn * 128 + r0) * K + c0;
  const unsigned short* Brow1 = Bw + (size_t)(bn * 128 + r1) * K + c1;

  f32x4 acc[4][4] = {};

  gl_lds16(Arow0, &smem[g0 * 8]);
  gl_lds16(Arow1, &smem[g1 * 8]);
  gl_lds16(Brow0, &smem[4096 + g0 * 8]);
  gl_lds16(Brow1, &smem[4096 + g1 * 8]);
  __syncthreads();

  for (int it = 0; it < 32; it++) {
    const int cur = (it & 1) * 8192;
    if (it + 1 < 32) {
      const int nxt = 8192 - cur;
      const int k1 = (it + 1) * 32;
      gl_lds16(Arow0 + k1, &smem[nxt + g0 * 8]);
      gl_lds16(Arow1 + k1, &smem[nxt + g1 * 8]);
      gl_lds16(Brow0 + k1, &smem[nxt + 4096 + g0 * 8]);
      gl_lds16(Brow1 + k1, &smem[nxt + 4096 + g1 * 8]);
    }
    const unsigned short* As = &smem[cur];
    const unsigned short* Bs = &smem[cur + 4096];

    bf16x8 af[4], bfr[4];
#pragma unroll
    for (int mt = 0; mt < 4; mt++)
      af[mt] = __builtin_bit_cast(
          bf16x8,
          *reinterpret_cast<const short8*>(&As[(wm + mt * 16 + lr) * 32 + (quad ^ rxor) * 8]));
#pragma unroll
    for (int nt = 0; nt < 4; nt++)
      bfr[nt] = __builtin_bit_cast(
          bf16x8,
          *reinterpret_cast<const short8*>(&Bs[(wn + nt * 16 + lr) * 32 + (quad ^ rxor) * 8]));
#pragma unroll
    for (int mt = 0; mt < 4; mt++)
#pragma unroll
      for (int nt = 0; nt < 4; nt++)
        acc[mt][nt] = __builtin_amdgcn_mfma_f32_16x16x32_bf16(af[mt], bfr[nt], acc[mt][nt], 0, 0, 0);
    __syncthreads();
  }

  // V transpose through LDS (reuses smem), write Vt[(b*16+h2)*64+d][s]
  const int b = bm >> 4;
  const int s0 = (bm & 15) * 128;
#pragma unroll
  for (int half = 0; half < 2; half++) {
    __syncthreads();
    if ((wave & 1) == half) {
#pragma unroll
      for (int nt = 0; nt < 4; nt++) {
#pragma unroll
        for (int mt = 0; mt < 4; mt++) {
#pragma unroll
          for (int r = 0; r < 4; r++) {
            int cl = nt * 16 + lr;                 // d within this 64-col half
            int rl = wm + mt * 16 + quad * 4 + r;  // s within 128-row tile
            smem[cl * 136 + rl] = f2bf_rne(acc[mt][nt][r]);
          }
        }
      }
    }
    __syncthreads();
    const int h2 = bn * 2 + half;
    const size_t rowbase = ((size_t)(b * N_HEADS + h2)) * HEAD_DIM;
#pragma unroll
    for (int i = 0; i < 4; i++) {
      int c = i * 256 + t;
      int d = c >> 4, s8 = (c & 15) * 8;
      uint4 v = *reinterpret_cast<const uint4*>(&smem[d * 136 + s8]);
      *reinterpret_cast<uint4*>(Vt + (rowbase + d) * SEQ + s0 + s8) = v;
    }
  }
}

// ---------------- O-projection GEMM: 128x128 tile, dbuf + XOR swizzle (r13 proven) --------
// T1: same-bm blocks co-XCD (A panel L2 reuse; B weight is only 2MB, refetch is cheap).
__global__ __launch_bounds__(256) void gemm_bt_f32(const unsigned short* __restrict__ A,
                                                   const unsigned short* __restrict__ Bw,
                                                   float* __restrict__ Cp,
                                                   int M, int N, int K) {
  __shared__ __align__(16) unsigned short smem[16384];
  const int t = threadIdx.x;
  const int flat = blockIdx.y * 8 + blockIdx.x;  // hw dispatch order, x fastest
  const int xcd = flat & 7, idx = flat >> 3;     // 512 = 8 * 64, bijective
  const int bm = xcd * 8 + (idx & 7);            // same-bm blocks share XCD
  const int bn = idx >> 3;
  const int wave = t >> 6, lane = t & 63;
  const int wm = (wave >> 1) * 64, wn = (wave & 1) * 64;
  const int lr = lane & 15, quad = lane >> 4;
  const int rxor = (lr >> 1) & 3;

  const int g0 = wave * 128 + lane, g1 = g0 + 64;
  const int r0 = g0 >> 2, c0 = (((g0 & 3) ^ ((r0 >> 1) & 3)) << 3);
  const int r1 = g1 >> 2, c1 = (((g1 & 3) ^ ((r1 >> 1) & 3)) << 3);
  const unsigned short* Arow0 = A + (size_t)(bm * 128 + r0) * K + c0;
  const unsigned short* Arow1 = A + (size_t)(bm * 128 + r1) * K + c1;
  const unsigned short* Brow0 = Bw + (size_t)(bn * 128 + r0) * K + c0;
  const unsigned short* Brow1 = Bw + (size_t)(bn * 128 + r1) * K + c1;

  f32x4 acc[4][4] = {};

  gl_lds16(Arow0, &smem[g0 * 8]);
  gl_lds16(Arow1, &smem[g1 * 8]);
  gl_lds16(Brow0, &smem[4096 + g0 * 8]);
  gl_lds16(Brow1, &smem[4096 + g1 * 8]);
  __syncthreads();

  for (int it = 0; it < 32; it++) {
    const int cur = (it & 1) * 8192;
    if (it + 1 < 32) {
      const int nxt = 8192 - cur;
      const int k1 = (it + 1) * 32;
      gl_lds16(Arow0 + k1, &smem[nxt + g0 * 8]);
      gl_lds16(Arow1 + k1, &smem[nxt + g1 * 8]);
      gl_lds16(Brow0 + k1, &smem[nxt + 4096 + g0 * 8]);
      gl_lds16(Brow1 + k1, &smem[nxt + 4096 + g1 * 8]);
    }
    const unsigned short* As = &smem[cur];
    const unsigned short* Bs = &smem[cur + 4096];

    bf16x8 af[4], bfr[4];
#pragma unroll
    for (int mt = 0; mt < 4; mt++)
      af[mt] = __builtin_bit_cast(
          bf16x8,
          *reinterpret_cast<const short8*>(&As[(wm + mt * 16 + lr) * 32 + (quad ^ rxor) * 8]));
#pragma unroll
    for (int nt = 0; nt < 4; nt++)
      bfr[nt] = __builtin_bit_cast(
          bf16x8,
          *reinterpret_cast<const short8*>(&Bs[(wn + nt * 16 + lr) * 32 + (quad ^ rxor) * 8]));
#pragma unroll
    for (int mt = 0; mt < 4; mt++)
#pragma unroll
      for (int nt = 0; nt < 4; nt++)
        acc[mt][nt] = __builtin_amdgcn_mfma_f32_16x16x32_bf16(af[mt], bfr[nt], acc[mt][nt], 0, 0, 0);
    __syncthreads();
  }

#pragma unroll
  for (int mt = 0; mt < 4; mt++) {
#pragma unroll
    for (int nt = 0; nt < 4; nt++) {
      int col = bn * 128 + wn + nt * 16 + lr;
#pragma unroll
      for (int r = 0; r < 4; r++) {
        int row = bm * 128 + wm + mt * 16 + quad * 4 + r;
        Cp[(size_t)row * N + col] = acc[mt][nt][r];
      }
    }
  }
}

// ---------------- causal flash attention v16: v14 + fully-masked-tile skip ----------------
// Occupancy lever exhausted (v15: launch_bounds(512,6) left occupancy at ~52%, perf flat).
// Reverted to best-measured (512,4). New: wave-uniform 'active' guard skips the ~1 fully
// masked diagonal tile per low wave (kv0 > m0+15 => all P==0, contributes nothing) —
// saves ~5% of MFMA+softmax issue. Barriers/prefetch unconditional (no divergence).
__global__ __launch_bounds__(512, 4) void attn_causal(const unsigned short* __restrict__ Q,
                                                      const unsigned short* __restrict__ Km,
                                                      const unsigned short* __restrict__ Vt,
                                                      unsigned short* __restrict__ O) {
  __shared__ __align__(16) unsigned short Kv[2][2][64 * 64];  // [buf][K=0/V=1], unpadded
  __shared__ __align__(16) unsigned short Ps[8][1024];        // per-wave P[q=0..15][k=0..63], swizzled

  const int bid = blockIdx.x;
  const int xcd = bid & 7, g = bid >> 3;  // grid 1024 = 8 XCDs x 128
  const int qt = 15 - (g >> 3);           // LPT: longest blocks (qt=15) dispatch first
  const int bh = xcd * 8 + (g & 7);       // all 16 qt-blocks of one (b,h) share XCD 'xcd'
  const int h = bh & 15;
  const int b = bh >> 4;

  const int t = threadIdx.x;
  const int wave = t >> 6, lane = t & 63;
  const int lr = lane & 15, quad = lane >> 4;
  const int cxor = lr & 7;

  const size_t base = (size_t)b * SEQ * D_MODEL + h * HEAD_DIM;
  const unsigned short* Qb = Q + base;
  const unsigned short* Kb = Km + base;
  const unsigned short* Vb = Vt + (size_t)(b * N_HEADS + h) * HEAD_DIM * SEQ;
  unsigned short* pw = &Ps[wave][0];

  const int srow = t >> 3;
  const int scol = ((t & 7) ^ (srow & 7)) << 3;
  const unsigned short* Kg = Kb + (size_t)srow * D_MODEL + scol;
  const unsigned short* Vg = Vb + (size_t)srow * SEQ + scol;

  const int m0 = qt * 128 + wave * 16;
  const int ntiles = (qt + 1) * 2;

  bf16x8 qf[2];
#pragma unroll
  for (int kk = 0; kk < 2; kk++)
    qf[kk] = __builtin_bit_cast(
        bf16x8,
        *reinterpret_cast<const short8*>(Qb + (size_t)(m0 + lr) * D_MODEL + kk * 32 + quad * 8));

  f32x4 o_acc[4] = {};
  float lsum = 0.f;

  gl_lds16(Kg, &Kv[0][0][t * 8]);
  gl_lds16(Vg, &Kv[0][1][t * 8]);

  for (int kt = 0; kt < ntiles; kt++) {
    const int cur = kt & 1;
    const int kv0 = kt * 64;
    __syncthreads();  // drains gl_lds into buf[cur]; orders buf[1-cur] reuse
    if (kt + 1 < ntiles) {
      gl_lds16(Kg + (size_t)(kv0 + 64) * D_MODEL, &Kv[1 - cur][0][t * 8]);
      gl_lds16(Vg + kv0 + 64, &Kv[1 - cur][1][t * 8]);
    }
    const unsigned short* Ks = &Kv[cur][0][0];
    const unsigned short* Vs = &Kv[cur][1][0];

    // wave-uniform: tile contributes iff it has at least one unmasked (q,k) pair
    const bool active = (kv0 <= m0 + 15);
    if (active) {
      // S^T: sAcc[j][r] = S[k = kv0+16j+4*quad+r][q = m0+lr]
      f32x4 sAcc[4] = {};
      __builtin_amdgcn_s_setprio(1);
#pragma unroll
      for (int kk = 0; kk < 2; kk++) {
        bf16x8 kf[4];
#pragma unroll
        for (int j = 0; j < 4; j++)
          kf[j] = __builtin_bit_cast(
              bf16x8, *reinterpret_cast<const short8*>(
                          &Ks[(j * 16 + lr) * 64 + ((kk * 4 + quad) ^ cxor) * 8]));
#pragma unroll
        for (int j = 0; j < 4; j++)
          sAcc[j] = __builtin_amdgcn_mfma_f32_16x16x32_bf16(kf[j], qf[kk], sAcc[j], 0, 0, 0);
      }
      __builtin_amdgcn_s_setprio(0);

      WAIT_LGKM0();  // prev tile's pf reads drained before overwriting pw
      const bool needmask = (kv0 + 63 > m0);  // wave-uniform
      const int kbase = kv0 - m0 + quad * 4;  // k_abs - m0 - r offset base
#pragma unroll
      for (int j = 0; j < 4; j++) {
        float e[4];
#pragma unroll
        for (int r = 0; r < 4; r++) e[r] = EXP2F(sAcc[j][r]);
        if (needmask) {
#pragma unroll
          for (int r = 0; r < 4; r++)
            if (kbase + 16 * j + r > lr) e[r] = 0.f;
        }
        lsum += (e[0] + e[1]) + (e[2] + e[3]);
        const unsigned int pk0 = cvtpk_bf16(e[0], e[1]);
        const unsigned int pk1 = cvtpk_bf16(e[2], e[3]);
        const int c = 4 * j + quad;  // 8B-granule index along k
        *reinterpret_cast<uint2*>(
            &pw[lr * 64 + (((c >> 1) ^ (lr & 7)) << 3) + ((c & 1) << 2)]) =
            make_uint2(pk0, pk1);
      }
      WAIT_LGKM0();  // P writes visible (same-wave RAW)

      __builtin_amdgcn_s_setprio(1);
#pragma unroll
      for (int kk = 0; kk < 2; kk++) {
        bf16x8 pf = __builtin_bit_cast(
            bf16x8, *reinterpret_cast<const short8*>(
                        &pw[lr * 64 + (((kk * 4 + quad) ^ (lr & 7)) << 3)]));
#pragma unroll
        for (int c = 0; c < 4; c++) {
          bf16x8 vv = __builtin_bit_cast(
              bf16x8, *reinterpret_cast<const short8*>(
                          &Vs[(c * 16 + lr) * 64 + ((kk * 4 + quad) ^ cxor) * 8]));
          o_acc[c] = __builtin_amdgcn_mfma_f32_16x16x32_bf16(pf, vv, o_acc[c], 0, 0, 0);
        }
      }
      __builtin_amdgcn_s_setprio(0);
    }
  }

  // lsum: lane holds partial for q=m0+lr over k in its quad slots; all-reduce over quads
  float l = lsum;
  l += __shfl_xor(l, 16, 64);
  l += __shfl_xor(l, 32, 64);  // every lane: full denom for q = m0 + lr
#pragma unroll
  for (int r = 0; r < 4; r++) {
    const float lq = __shfl(l, quad * 4 + r, 16);  // denom for q = m0 + quad*4 + r
    const float inv = 1.f / lq;
    const int qpos = m0 + quad * 4 + r;
#pragma unroll
    for (int c = 0; c < 4; c++)
      O[base + (size_t)qpos * D_MODEL + c * 16 + lr] = f2bf_rne(o_acc[c][r] * inv);
  }
}

// ---------------- launch ----------------
extern "C" void kernel_launch(void* const* d_in, const int* in_sizes, int n_in,
                              void* d_out, int out_size, void* d_ws, size_t ws_size,
                              hipStream_t stream) {
  const float* x  = (const float*)d_in[0];
  const float* Wq = (const float*)d_in[1];
  const float* Wk = (const float*)d_in[2];
  const float* Wv = (const float*)d_in[3];
  const float* Wo = (const float*)d_in[4];
  float* out = (float*)d_out;

  char* ws = (char*)d_ws;
  const size_t SZ_X = (size_t)M_ROWS * D_MODEL * 2;   // 16 MB
  const size_t SZ_W = (size_t)D_MODEL * D_MODEL * 2;  //  2 MB
  unsigned short* xb  = (unsigned short*)(ws);
  unsigned short* wqb = (unsigned short*)(ws + SZ_X);
  unsigned short* wkb = (unsigned short*)(ws + SZ_X + 1 * SZ_W);
  unsigned short* wvb = (unsigned short*)(ws + SZ_X + 2 * SZ_W);
  unsigned short* wob = (unsigned short*)(ws + SZ_X + 3 * SZ_W);
  unsigned short* Qb  = (unsigned short*)(ws + 1 * SZ_X + 4 * SZ_W);
  unsigned short* Kb  = (unsigned short*)(ws + 2 * SZ_X + 4 * SZ_W);
  unsigned short* Vt  = (unsigned short*)(ws + 3 * SZ_X + 4 * SZ_W);
  unsigned short* Ob  = xb;  // x dead after QKV projection

  cvt_all<<<12288, 256, 0, stream>>>(x, Wq, Wk, Wv, Wo, xb, wqb, wkb, wvb, wob);

  qk_gemm8<<<256, 512, 0, stream>>>(xb, wqb, wkb, Qb, Kb);

  v_gemm<<<dim3(8, 64), 256, 0, stream>>>(xb, wvb, Vt);

  attn_causal<<<1024, 512, 0, stream>>>(Qb, Kb, Vt, Ob);

  gemm_bt_f32<<<dim3(8, 64), 256, 0, stream>>>(Ob, wob, out, M_ROWS, D_MODEL, D_MODEL);
}